// Round 9
// baseline (875.621 us; speedup 1.0000x reference)
//
#include <hip/hip_runtime.h>
#include <hip/hip_bf16.h>
#include <hip/hip_fp16.h>

typedef __hip_bfloat16 bf16;
typedef __attribute__((ext_vector_type(8))) __bf16 bf16x8;   // 8 bf16 = 4 VGPRs (MFMA A/B frag)
typedef __attribute__((ext_vector_type(4))) __bf16 bf16x4;   // 8B packed store
typedef __attribute__((ext_vector_type(4))) float f32x4;     // MFMA C/D frag
typedef __attribute__((ext_vector_type(4))) float f4;        // indexable float4

#define NBLK 1024  // persistent grid: LDS 34.8KB -> 4 blocks/CU, launch_bounds(256,4) => all resident

// async global->LDS, 16B per lane. LDS dest must be wave-uniform base (lane*16 auto).
__device__ __forceinline__ void gload_lds16(const bf16* g, bf16* l)
{
    __builtin_amdgcn_global_load_lds((const __attribute__((address_space(1))) void*)g,
                                     (__attribute__((address_space(3))) void*)l, 16, 0, 0);
}

// ---------------------------------------------------------------------------
// Grid barrier k: monotonic per-barrier counter (no reset -> race-free).
// RELAXED atomics (coherence-point ops, no per-poll cache invalidate);
// exactly one release fence before and one acquire fence after per block.
// Counters zeroed by hipMemsetAsync each launch; 128B-strided.
// ---------------------------------------------------------------------------
__device__ __forceinline__ void grid_sync(int* bar, int k)
{
    __builtin_amdgcn_fence(__ATOMIC_RELEASE, "agent");   // flush this block's writes
    __syncthreads();
    if (threadIdx.x == 0) {
        int* c = bar + (k << 5);
        __hip_atomic_fetch_add(c, 1, __ATOMIC_RELAXED, __HIP_MEMORY_SCOPE_AGENT);
        while (__hip_atomic_load(c, __ATOMIC_RELAXED, __HIP_MEMORY_SCOPE_AGENT) < NBLK)
            __builtin_amdgcn_s_sleep(16);
    }
    __syncthreads();
    __builtin_amdgcn_fence(__ATOMIC_ACQUIRE, "agent");   // invalidate caches once
}

// ---------------------------------------------------------------------------
// prep_kernel: (a) CPB MLP, (b) 5 weight transposes (32x32 LDS tile),
// (c) both downsamples. grid = ncpb + 768 + 4096.
// ---------------------------------------------------------------------------
__global__ __launch_bounds__(256) void prep_kernel(
    const float* __restrict__ tab, const float* __restrict__ w1, const float* __restrict__ b1,
    const float* __restrict__ w2, const float* __restrict__ b2, float* __restrict__ cpbout, int L, int ncpb,
    const float* __restrict__ Wq, const float* __restrict__ Wkv, const float* __restrict__ Wo,
    const float* __restrict__ fw1, const float* __restrict__ fw2,
    bf16* __restrict__ WqT, bf16* __restrict__ WkvT, bf16* __restrict__ WoT,
    bf16* __restrict__ W1T, bf16* __restrict__ W2T,
    const float* __restrict__ qsrc, const float* __restrict__ kvsrc,
    bf16* __restrict__ qdst, bf16* __restrict__ kvdst)
{
    __shared__ float o[32][33];
    const int t = threadIdx.x;
    int bid = blockIdx.x;
    if (bid < ncpb) {
        int l = bid * 32 + (t >> 3);
        int js = t & 7;
        bool valid = l < L;
        float t0 = valid ? tab[2 * l] : 0.f, t1 = valid ? tab[2 * l + 1] : 0.f;
        float acc[8];
#pragma unroll
        for (int hh = 0; hh < 8; ++hh) acc[hh] = 0.f;
        for (int j = js; j < 512; j += 8) {
            float hv = fmaxf(t0 * w1[j] + t1 * w1[512 + j] + b1[j], 0.f);
            f4 w2a = *(const f4*)&w2[j * 8];
            f4 w2b = *(const f4*)&w2[j * 8 + 4];
#pragma unroll
            for (int hh = 0; hh < 4; ++hh) { acc[hh] += hv * w2a[hh]; acc[4 + hh] += hv * w2b[hh]; }
        }
#pragma unroll
        for (int d = 1; d < 8; d <<= 1)
#pragma unroll
            for (int hh = 0; hh < 8; ++hh) acc[hh] += __shfl_xor(acc[hh], d);
        if (js == 0 && valid)
#pragma unroll
            for (int hh = 0; hh < 8; ++hh) cpbout[(size_t)hh * L + l] = acc[hh] + b2[hh];
        return;
    }
    bid -= ncpb;
    if (bid < 768) {
        const float* W; bf16* WT; int K, N, base;
        if (bid < 64)        { W = Wq;  WT = WqT;  K = 256;  N = 256;  base = 0; }
        else if (bid < 192)  { W = Wkv; WT = WkvT; K = 256;  N = 512;  base = 64; }
        else if (bid < 256)  { W = Wo;  WT = WoT;  K = 256;  N = 256;  base = 192; }
        else if (bid < 512)  { W = fw1; WT = W1T;  K = 256;  N = 1024; base = 256; }
        else                 { W = fw2; WT = W2T;  K = 1024; N = 256;  base = 512; }
        int lid = bid - base;
        int tn = N >> 5;
        int k0 = (lid / tn) << 5, n0 = (lid % tn) << 5;
        {
            int r = t >> 3, cc = (t & 7) * 4;
            *(f4*)&o[r][cc] = *(const f4*)&W[(size_t)(k0 + r) * N + n0 + cc];
        }
        __syncthreads();
        {
            int n = t >> 3, kk = (t & 7) * 4;
            bf16 tmp[4];
#pragma unroll
            for (int i = 0; i < 4; ++i) tmp[i] = (bf16)o[kk + i][n];
            *(bf16x4*)&WT[(size_t)(n0 + n) * K + k0 + kk] = *(const bf16x4*)tmp;
        }
        return;
    }
    bid -= 768;
    {
        const float* src = bid < 2048 ? qsrc : kvsrc;
        bf16* dst = bid < 2048 ? qdst : kvdst;
        int bb2 = bid & 2047;
        int cc = bb2 & 7, i = (bb2 >> 3) & 31, b = bb2 >> 8;
#pragma unroll
        for (int p = 0; p < 4; ++p) {
            int id = p * 256 + t;
            int c = id >> 5, j = id & 31;
            const float* r = src + ((size_t)(b * 256 + cc * 32 + c) * 128 + 4 * i + 1) * 128 + 4 * j;
            float4 r1 = *(const float4*)r;
            float4 r2 = *(const float4*)(r + 128);
            o[c][j] = 0.25f * (r1.y + r1.z + r2.y + r2.z);
        }
        __syncthreads();
        {
            int j = t >> 3, c4 = (t & 7) * 4;
            bf16 tmp[4];
#pragma unroll
            for (int k = 0; k < 4; ++k) tmp[k] = (bf16)fmaxf(o[c4 + k][j], 0.f);
            *(bf16x4*)&dst[(size_t)(b * 1024 + i * 32 + j) * 256 + cc * 32 + c4] = *(const bf16x4*)tmp;
        }
    }
}

// ---------------------------------------------------------------------------
// GEMM core (single-buffer): tile BM x BN, BK=64, 4 waves (2x2).
// Linear LDS dest + XOR-swizzled global source; read applies the same XOR.
// ---------------------------------------------------------------------------
template<int BM, int BN>
__device__ __forceinline__ void gemm_core(
    const bf16* __restrict__ A, const bf16* __restrict__ BT, int K,
    int m0, int n0, bf16* As, bf16* Bs, f32x4 (&acc)[BM / 32][BN / 32])
{
    constexpr int MI = BM / 32, NJ = BN / 32;
    const int tid = threadIdx.x;
    const int lane = tid & 63, wid = tid >> 6;
    const int lo = lane & 15, hi = lane >> 4;
    const int wr = wid >> 1, wc = wid & 1;
#pragma unroll
    for (int i = 0; i < MI; ++i)
#pragma unroll
        for (int j = 0; j < NJ; ++j) acc[i][j] = f32x4{0.f, 0.f, 0.f, 0.f};

    for (int k0 = 0; k0 < K; k0 += 64) {
        __syncthreads();
#pragma unroll
        for (int p = 0; p < BM / 32; ++p) {
            int f = p * 256 + wid * 64 + lane;
            int row = f >> 3, cs = f & 7;
            gload_lds16(&A[(size_t)(m0 + row) * K + k0 + ((cs ^ (row & 7)) * 8)],
                        As + (size_t)(p * 256 + wid * 64) * 8);
        }
#pragma unroll
        for (int p = 0; p < BN / 32; ++p) {
            int f = p * 256 + wid * 64 + lane;
            int row = f >> 3, cs = f & 7;
            gload_lds16(&BT[(size_t)(n0 + row) * K + k0 + ((cs ^ (row & 7)) * 8)],
                        Bs + (size_t)(p * 256 + wid * 64) * 8);
        }
        __syncthreads();   // drains vmcnt(0) for global_load_lds
        bf16x8 af[2][MI], bfr[2][NJ];
#pragma unroll
        for (int kk = 0; kk < 2; ++kk) {
#pragma unroll
            for (int i = 0; i < MI; ++i) {
                int row = wr * (BM / 2) + i * 16 + lo;
                af[kk][i] = *(const bf16x8*)&As[row * 64 + (((kk * 4 + hi) ^ (lo & 7)) * 8)];
            }
#pragma unroll
            for (int j = 0; j < NJ; ++j) {
                int row = wc * (BN / 2) + j * 16 + lo;
                bfr[kk][j] = *(const bf16x8*)&Bs[row * 64 + (((kk * 4 + hi) ^ (lo & 7)) * 8)];
            }
        }
#pragma unroll
        for (int kk = 0; kk < 2; ++kk)
#pragma unroll
            for (int i = 0; i < MI; ++i)
#pragma unroll
                for (int j = 0; j < NJ; ++j)
                    acc[i][j] = __builtin_amdgcn_mfma_f32_16x16x32_bf16(af[kk][i], bfr[kk][j], acc[i][j], 0, 0, 0);
    }
    __syncthreads();   // protect LDS reuse by the next phase-iteration
}

// ---------------------------------------------------------------------------
// Phase 1: q/kv projections (+V->vT transpose epilogue) + bias_gather rider.
// vb in [0,2560): bx = vb&127, by = vb>>7.
// ---------------------------------------------------------------------------
__device__ void phase_qkv(char* smem, int vb,
    const bf16* qt, const bf16* WqT, const float* bq, bf16* qhb,
    const bf16* kvt, const bf16* WkvT, const float* bkv, bf16* kvpb, bf16* vT,
    const int* ridx, const float* cpbh, bf16* biasF, int L)
{
    const int tid = threadIdx.x;
    const int lane = tid & 63, wid = tid >> 6;
    const int lo = lane & 15, hi = lane >> 4;
    const int bx = vb & 127, by = vb >> 7;
    if (by >= 12) {
        __syncthreads();               // LDS reuse guard
        int* rix = (int*)smem;         // [32][32]
        int id = (by - 12) * 128 + bx;
        int qtb = id >> 5, mt = id & 31;
        {
            int q = tid >> 3, m4 = (tid & 7) * 4;
            *(int4*)&rix[q * 32 + m4] = *(const int4*)&ridx[(size_t)(qtb * 32 + q) * 1024 + mt * 32 + m4];
        }
        __syncthreads();
        const int qj = (tid >> 6) & 1, hg = tid >> 7;
        int lidx[8];
#pragma unroll
        for (int j = 0; j < 8; ++j) {
            int kf = j >> 2, r = j & 3;
            lidx[j] = rix[(qj * 16 + lo) * 32 + kf * 16 + hi * 4 + r];
        }
#pragma unroll
        for (int hh = 0; hh < 4; ++hh) {
            int h = hg * 4 + hh;
            const float* ct = cpbh + (size_t)h * L;
            bf16 vals[8];
#pragma unroll
            for (int j = 0; j < 8; ++j) vals[j] = (bf16)ct[lidx[j]];
            size_t off = ((((size_t)(h * 32 + qtb) * 32 + mt) * 2 + qj) * 64 + lane) * 8;
            *(bf16x8*)&biasF[off] = *(const bf16x8*)vals;
        }
        __syncthreads();               // LDS reuse guard (rix vs next iter)
        return;
    }
    bf16* As = (bf16*)smem;
    bf16* Bs = (bf16*)(smem + 8192);
    const int wr = wid >> 1, wc = wid & 1;
    const bf16 *A, *BT; const float* bias; int n0;
    if (by < 4)      { A = qt;  BT = WqT;  bias = bq;  n0 = by * 64; }
    else             { A = kvt; BT = WkvT; bias = bkv; n0 = (by - 4) * 64; }
    const int m0 = bx * 64;
    f32x4 acc[2][2];
    gemm_core<64, 64>(A, BT, 256, m0, n0, As, Bs, acc);
#pragma unroll
    for (int i = 0; i < 2; ++i)
#pragma unroll
        for (int j = 0; j < 2; ++j) {
            int col = n0 + wc * 32 + j * 16 + lo;
            float bv = bias[col];
            if (by < 4) {
#pragma unroll
                for (int r = 0; r < 4; ++r) {
                    int row = m0 + wr * 32 + i * 16 + hi * 4 + r;
                    qhb[(size_t)row * 256 + col] = (bf16)(acc[i][j][r] + bv);
                }
            } else if (by < 8) {
#pragma unroll
                for (int r = 0; r < 4; ++r) {
                    int row = m0 + wr * 32 + i * 16 + hi * 4 + r;
                    kvpb[(size_t)row * 512 + col] = (bf16)(acc[i][j][r] + bv);
                }
            } else {
                int vcol = col - 256;
                int h = vcol >> 5, d = vcol & 31;
                int b = m0 >> 10;
                int mbase = (m0 & 1023) + wr * 32 + i * 16 + hi * 4;
                bf16 tmp[4];
#pragma unroll
                for (int r = 0; r < 4; ++r) tmp[r] = (bf16)(acc[i][j][r] + bv);
                *(bf16x4*)&vT[(size_t)((b * 8 + h) * 32 + d) * 1024 + mbase] = *(const bf16x4*)tmp;
            }
        }
}

// ---------------------------------------------------------------------------
// Phase 2: flash attention (swapped QK, 4-way key split + LDS merge).
// vb in [0,2048): qt = vb&31, h = (vb>>5)&7, b = vb>>8.
// ---------------------------------------------------------------------------
__device__ void phase_attn(char* smem, int vb,
    const bf16* qh, const bf16* kvp, const bf16* vT,
    const bf16* biasF, bf16* attnout)
{
    bf16* Ps = (bf16*)smem;                       // [4][32*40]
    __half* accs = (__half*)(smem + 10240);       // [4][32][34]
    float* pm = (float*)(smem + 18944);           // [4][32]
    float* pl = (float*)(smem + 19456);           // [4][32]
    const int tid = threadIdx.x, lane = tid & 63, wid = tid >> 6;
    const int lo = lane & 15, hi = lane >> 4;
    const int qt = vb & 31, n0 = qt * 32;
    const int h = (vb >> 5) & 7;
    const int b = vb >> 8;
    const float scale = 0.17677669529663687f;  // 1/sqrt(32)
    const f32x4 zero4 = {0.f, 0.f, 0.f, 0.f};

    bf16x8 qf[2];
#pragma unroll
    for (int qj = 0; qj < 2; ++qj)
        qf[qj] = *(const bf16x8*)&qh[(size_t)(b * 1024 + n0 + qj * 16 + lo) * 256 + h * 32 + hi * 8];

    f32x4 acc[2][2];
#pragma unroll
    for (int i = 0; i < 2; ++i)
#pragma unroll
        for (int j = 0; j < 2; ++j) acc[i][j] = zero4;
    float mrow[2] = {-1e30f, -1e30f}, lrow[2] = {0.f, 0.f};

    bf16* Pw = Ps + wid * (32 * 40);

    for (int t = wid; t < 32; t += 4) {
        const int m0 = t * 32;
        bf16x8 kfr0 = *(const bf16x8*)&kvp[(size_t)(b * 1024 + m0 + lo) * 512 + h * 32 + hi * 8];
        bf16x8 kfr1 = *(const bf16x8*)&kvp[(size_t)(b * 1024 + m0 + 16 + lo) * 512 + h * 32 + hi * 8];
        bf16x8 va0 = *(const bf16x8*)&vT[(size_t)((b * 8 + h) * 32 + lo) * 1024 + m0 + hi * 8];
        bf16x8 va1 = *(const bf16x8*)&vT[(size_t)((b * 8 + h) * 32 + 16 + lo) * 1024 + m0 + hi * 8];
        size_t boff = (((size_t)(h * 32 + qt) * 32 + t) * 2 * 64 + lane) * 8;
        bf16x8 bv0 = *(const bf16x8*)&biasF[boff];
        bf16x8 bv1 = *(const bf16x8*)&biasF[boff + 512];

        f32x4 s[2][2];
        s[0][0] = __builtin_amdgcn_mfma_f32_16x16x32_bf16(kfr0, qf[0], zero4, 0, 0, 0);
        s[0][1] = __builtin_amdgcn_mfma_f32_16x16x32_bf16(kfr0, qf[1], zero4, 0, 0, 0);
        s[1][0] = __builtin_amdgcn_mfma_f32_16x16x32_bf16(kfr1, qf[0], zero4, 0, 0, 0);
        s[1][1] = __builtin_amdgcn_mfma_f32_16x16x32_bf16(kfr1, qf[1], zero4, 0, 0, 0);
#pragma unroll
        for (int kf = 0; kf < 2; ++kf)
#pragma unroll
            for (int r = 0; r < 4; ++r) {
                s[kf][0][r] = s[kf][0][r] * scale + (float)bv0[kf * 4 + r];
                s[kf][1][r] = s[kf][1][r] * scale + (float)bv1[kf * 4 + r];
            }
#pragma unroll
        for (int qj = 0; qj < 2; ++qj) {
            float mx = fmaxf(fmaxf(fmaxf(s[0][qj][0], s[0][qj][1]), fmaxf(s[0][qj][2], s[0][qj][3])),
                             fmaxf(fmaxf(s[1][qj][0], s[1][qj][1]), fmaxf(s[1][qj][2], s[1][qj][3])));
            mx = fmaxf(mx, __shfl_xor(mx, 16));
            mx = fmaxf(mx, __shfl_xor(mx, 32));
            float mnew = fmaxf(mrow[qj], mx);
            float alpha = __expf(mrow[qj] - mnew);
            float rs = 0.f;
#pragma unroll
            for (int kf = 0; kf < 2; ++kf)
#pragma unroll
                for (int r = 0; r < 4; ++r) {
                    float p = __expf(s[kf][qj][r] - mnew);
                    s[kf][qj][r] = p;
                    rs += p;
                }
            rs += __shfl_xor(rs, 16);
            rs += __shfl_xor(rs, 32);
            lrow[qj] = lrow[qj] * alpha + rs;
            mrow[qj] = mnew;
#pragma unroll
            for (int di = 0; di < 2; ++di)
#pragma unroll
                for (int r = 0; r < 4; ++r) acc[di][qj][r] *= alpha;
        }
#pragma unroll
        for (int qj = 0; qj < 2; ++qj)
#pragma unroll
            for (int kf = 0; kf < 2; ++kf)
#pragma unroll
                for (int r = 0; r < 4; ++r)
                    Pw[(qj * 16 + lo) * 40 + kf * 16 + hi * 4 + r] = (bf16)s[kf][qj][r];
        bf16x8 pb0 = *(const bf16x8*)&Pw[lo * 40 + hi * 8];
        bf16x8 pb1 = *(const bf16x8*)&Pw[(16 + lo) * 40 + hi * 8];
        acc[0][0] = __builtin_amdgcn_mfma_f32_16x16x32_bf16(va0, pb0, acc[0][0], 0, 0, 0);
        acc[0][1] = __builtin_amdgcn_mfma_f32_16x16x32_bf16(va0, pb1, acc[0][1], 0, 0, 0);
        acc[1][0] = __builtin_amdgcn_mfma_f32_16x16x32_bf16(va1, pb0, acc[1][0], 0, 0, 0);
        acc[1][1] = __builtin_amdgcn_mfma_f32_16x16x32_bf16(va1, pb1, acc[1][1], 0, 0, 0);
    }
#pragma unroll
    for (int di = 0; di < 2; ++di)
#pragma unroll
        for (int qj = 0; qj < 2; ++qj)
#pragma unroll
            for (int r = 0; r < 4; ++r)
                accs[((wid * 32) + di * 16 + hi * 4 + r) * 34 + qj * 16 + lo] = __float2half(acc[di][qj][r]);
    if (hi == 0) {
#pragma unroll
        for (int qj = 0; qj < 2; ++qj) {
            pm[wid * 32 + qj * 16 + lo] = mrow[qj];
            pl[wid * 32 + qj * 16 + lo] = lrow[qj];
        }
    }
    __syncthreads();
    int q = tid >> 3, d0 = (tid & 7) * 4;
    float M = fmaxf(fmaxf(pm[q], pm[32 + q]), fmaxf(pm[64 + q], pm[96 + q]));
    float f0 = __expf(pm[q] - M), f1 = __expf(pm[32 + q] - M);
    float f2 = __expf(pm[64 + q] - M), f3 = __expf(pm[96 + q] - M);
    float inv = 1.f / (pl[q] * f0 + pl[32 + q] * f1 + pl[64 + q] * f2 + pl[96 + q] * f3);
    bf16 tmp[4];
#pragma unroll
    for (int j = 0; j < 4; ++j) {
        int d = d0 + j;
        float o = f0 * (float)accs[(0 * 32 + d) * 34 + q] + f1 * (float)accs[(1 * 32 + d) * 34 + q] +
                  f2 * (float)accs[(2 * 32 + d) * 34 + q] + f3 * (float)accs[(3 * 32 + d) * 34 + q];
        tmp[j] = (bf16)(o * inv);
    }
    *(bf16x4*)&attnout[(size_t)(b * 1024 + n0 + q) * 256 + h * 32 + d0] = *(const bf16x4*)tmp;
    __syncthreads();   // LDS reuse guard across vb iterations
}

// ---------------------------------------------------------------------------
// Phase 3/4: plain GEMM phases (Wo: 64x64; FFN1: 128x64 + gelu).
// ---------------------------------------------------------------------------
template<int BM, int BN>
__device__ void phase_gemm(char* smem, int bx, int by,
    const bf16* A, const bf16* BT, const float* bias, bf16* Cb, int N, int K, int act)
{
    bf16* As = (bf16*)smem;
    bf16* Bs = (bf16*)(smem + BM * 64 * 2);
    constexpr int MI = BM / 32, NJ = BN / 32;
    const int tid = threadIdx.x;
    const int lane = tid & 63, wid = tid >> 6;
    const int lo = lane & 15, hi = lane >> 4;
    const int m0 = bx * BM, n0 = by * BN;
    const int wr = wid >> 1, wc = wid & 1;
    f32x4 acc[MI][NJ];
    gemm_core<BM, BN>(A, BT, K, m0, n0, As, Bs, acc);
#pragma unroll
    for (int i = 0; i < MI; ++i)
#pragma unroll
        for (int j = 0; j < NJ; ++j) {
            int col = n0 + wc * (BN / 2) + j * 16 + lo;
            float bv = bias[col];
#pragma unroll
            for (int r = 0; r < 4; ++r) {
                int row = m0 + wr * (BM / 2) + i * 16 + hi * 4 + r;
                float v = acc[i][j][r] + bv;
                if (act == 1) v = 0.5f * v * (1.f + erff(v * 0.70710678118654752f));
                Cb[(size_t)row * N + col] = (bf16)v;
            }
        }
}

// ---------------------------------------------------------------------------
// Phase 5: FFN2 + residual + LayerNorm + transpose. vb in [0,512): m0 = vb*16.
// buf ALIASES As/Bs (dead after k-loop) -> LDS union stays 34816 B.
// ---------------------------------------------------------------------------
__device__ void phase_ffn2ln(char* smem, int vb,
    const bf16* A, const bf16* BT, const float* bias, const bf16* resid,
    const float* g, const float* bb, bf16* ysp)
{
    bf16* As = (bf16*)smem;                 // 16*64
    bf16* Bs = (bf16*)(smem + 2048);        // 256*64 (ends at 34816)
    float (*buf)[260] = (float(*)[260])smem;   // [16][260] = 16640 B, aliases As/Bs
    const int tid = threadIdx.x;
    const int lane = tid & 63, wid = tid >> 6;
    const int lo = lane & 15, hi = lane >> 4;
    const int m0 = vb * 16;
    f32x4 acc[4];
#pragma unroll
    for (int j = 0; j < 4; ++j) acc[j] = f32x4{0.f, 0.f, 0.f, 0.f};

    for (int k0 = 0; k0 < 1024; k0 += 64) {
        __syncthreads();
        if (tid < 128) {
            int row = tid >> 3, cs = tid & 7;
            gload_lds16(&A[(size_t)(m0 + row) * 1024 + k0 + ((cs ^ (row & 7)) * 8)],
                        As + (size_t)(wid * 64) * 8);
        }
#pragma unroll
        for (int p = 0; p < 8; ++p) {
            int f = p * 256 + tid, row = f >> 3, cs = f & 7;
            gload_lds16(&BT[(size_t)row * 1024 + k0 + ((cs ^ (row & 7)) * 8)],
                        Bs + (size_t)(p * 256 + wid * 64) * 8);
        }
        __syncthreads();
        bf16x8 af[2], bfr[2][4];
#pragma unroll
        for (int kk = 0; kk < 2; ++kk) {
            af[kk] = *(const bf16x8*)&As[lo * 64 + (((kk * 4 + hi) ^ (lo & 7)) * 8)];
#pragma unroll
            for (int j = 0; j < 4; ++j) {
                int row = wid * 64 + j * 16 + lo;
                bfr[kk][j] = *(const bf16x8*)&Bs[row * 64 + (((kk * 4 + hi) ^ (lo & 7)) * 8)];
            }
        }
#pragma unroll
        for (int kk = 0; kk < 2; ++kk)
#pragma unroll
            for (int j = 0; j < 4; ++j)
                acc[j] = __builtin_amdgcn_mfma_f32_16x16x32_bf16(af[kk], bfr[kk][j], acc[j], 0, 0, 0);
    }
    __syncthreads();   // all LDS reads of As/Bs done before buf overwrites them
#pragma unroll
    for (int j = 0; j < 4; ++j) {
        int col = wid * 64 + j * 16 + lo;
        float bv = bias[col];
#pragma unroll
        for (int r = 0; r < 4; ++r) {
            int lr = hi * 4 + r;
            buf[lr][col] = acc[j][r] + bv + (float)resid[(size_t)(m0 + lr) * 256 + col];
        }
    }
    __syncthreads();
#pragma unroll
    for (int rr = 0; rr < 4; ++rr) {
        int row = wid * 4 + rr;
        f4 x = *(const f4*)&buf[row][lane * 4];
        float s = x[0] + x[1] + x[2] + x[3];
#pragma unroll
        for (int d = 1; d < 64; d <<= 1) s += __shfl_xor(s, d);
        float mean = s * (1.f / 256.f);
        f4 dv = {x[0] - mean, x[1] - mean, x[2] - mean, x[3] - mean};
        float s2 = dv[0] * dv[0] + dv[1] * dv[1] + dv[2] * dv[2] + dv[3] * dv[3];
#pragma unroll
        for (int d = 1; d < 64; d <<= 1) s2 += __shfl_xor(s2, d);
        float rstd = rsqrtf(s2 * (1.f / 256.f) + 1e-5f);
        f4 o = {dv[0] * rstd, dv[1] * rstd, dv[2] * rstd, dv[3] * rstd};
        *(f4*)&buf[row][lane * 4] = o;
    }
    __syncthreads();
    float gc = g[tid], bc = bb[tid];
    int b = m0 >> 10, n0l = m0 & 1023;
    bf16* dst = &ysp[((size_t)(b * 256 + tid) << 10) + n0l];
#pragma unroll
    for (int p = 0; p < 2; ++p) {
        bf16 tmp[8];
#pragma unroll
        for (int k = 0; k < 8; ++k) tmp[k] = (bf16)(buf[p * 8 + k][tid] * gc + bc);
        *(bf16x8*)&dst[p * 8] = *(const bf16x8*)tmp;
    }
}

// ---------------------------------------------------------------------------
// Persistent middle kernel: 5 phases with cheap relaxed-poll grid barriers.
// 1024 blocks x 256 threads; LDS 34816 B -> 4 blocks/CU; VGPR capped by
// launch_bounds(256,4) -> all 1024 blocks co-resident, no deadlock.
// ---------------------------------------------------------------------------
__global__ __launch_bounds__(256, 4) void mid_kernel(
    const bf16* __restrict__ qt, const bf16* __restrict__ WqT, const float* __restrict__ bq,
    bf16* __restrict__ qhb,
    const bf16* __restrict__ kvt, const bf16* __restrict__ WkvT, const float* __restrict__ bkv,
    bf16* __restrict__ kvpb, bf16* __restrict__ vT,
    const int* __restrict__ ridx, const float* __restrict__ cpbh, bf16* __restrict__ biasF, int L,
    bf16* __restrict__ attnb,
    const bf16* __restrict__ WoT, const float* __restrict__ bo, bf16* __restrict__ outb,
    const bf16* __restrict__ W1T, const float* __restrict__ fb1, bf16* __restrict__ ffh,
    const bf16* __restrict__ W2T, const float* __restrict__ fb2,
    const float* __restrict__ lng, const float* __restrict__ lnb, bf16* __restrict__ ysp,
    int* __restrict__ bar)
{
    __shared__ __align__(16) char smem[34816];
    // phase 1: q/kv projections + vT + bias gather  (2560 vblocks)
    for (int vb = blockIdx.x; vb < 2560; vb += NBLK)
        phase_qkv(smem, vb, qt, WqT, bq, qhb, kvt, WkvT, bkv, kvpb, vT, ridx, cpbh, biasF, L);
    grid_sync(bar, 0);
    // phase 2: attention  (2048 vblocks)
    for (int vb = blockIdx.x; vb < 2048; vb += NBLK)
        phase_attn(smem, vb, qhb, kvpb, vT, biasF, attnb);
    grid_sync(bar, 1);
    // phase 3: out = attn @ Wo + bo  (512 vblocks)
    for (int vb = blockIdx.x; vb < 512; vb += NBLK)
        phase_gemm<64, 64>(smem, vb & 127, vb >> 7, attnb, WoT, bo, outb, 256, 256, 0);
    grid_sync(bar, 2);
    // phase 4: ffh = gelu(out @ W1 + b1)  (1024 vblocks; overwrites biasF)
    for (int vb = blockIdx.x; vb < 1024; vb += NBLK)
        phase_gemm<128, 64>(smem, vb & 63, vb >> 6, outb, W1T, fb1, ffh, 1024, 256, 1);
    grid_sync(bar, 3);
    // phase 5: ysp = LN(ffh @ W2 + b2 + out), transposed bf16  (512 vblocks)
    for (int vb = blockIdx.x; vb < 512; vb += NBLK)
        phase_ffn2ln(smem, vb, ffh, W2T, fb2, outb, lng, lnb, ysp);
}

// ---------------------------------------------------------------------------
// Bilinear 32x32 -> 128x128 (align_corners=False, edge clamp) + ReLU + x.
// ---------------------------------------------------------------------------
__global__ __launch_bounds__(256) void upsample_kernel(const float* __restrict__ x,
    const bf16* __restrict__ ysp, float* __restrict__ out)
{
    int idx = blockIdx.x * 256 + threadIdx.x;
    int w4 = idx & 31; int r1 = idx >> 5;
    int hh = r1 & 127; int r2 = r1 >> 7;
    int c = r2 & 255; int b = r2 >> 8;
    float chh = 0.25f * hh - 0.375f;
    float fi = floorf(chh);
    float fh = chh - fi;
    int i0 = (int)fi;
    int ia = i0 < 0 ? 0 : i0;
    int ib = (i0 + 1) > 31 ? 31 : (i0 + 1);
    const bf16* yr = ysp + ((size_t)(b * 256 + c) << 10);
    const bf16* ra = yr + ia * 32;
    const bf16* rb = yr + ib * 32;
    f4 xv = *(const f4*)&x[(size_t)idx * 4];
    f4 o;
#pragma unroll
    for (int k = 0; k < 4; ++k) {
        int ww = w4 * 4 + k;
        float cww = 0.25f * ww - 0.375f;
        float fj = floorf(cww);
        float fw = cww - fj;
        int j0 = (int)fj;
        int ja = j0 < 0 ? 0 : j0;
        int jb = (j0 + 1) > 31 ? 31 : (j0 + 1);
        float v = (1.f - fh) * ((1.f - fw) * (float)ra[ja] + fw * (float)ra[jb]) +
                  fh * ((1.f - fw) * (float)rb[ja] + fw * (float)rb[jb]);
        o[k] = xv[k] + fmaxf(v, 0.f);
    }
    *(f4*)&out[(size_t)idx * 4] = o;
}

// ---------------------------------------------------------------------------
extern "C" void kernel_launch(void* const* d_in, const int* in_sizes, int n_in,
                              void* d_out, int out_size, void* d_ws, size_t ws_size,
                              hipStream_t stream)
{
    (void)n_in; (void)out_size; (void)ws_size;
    const float* q    = (const float*)d_in[0];
    const float* kv   = (const float*)d_in[1];
    const int*   ridx = (const int*)d_in[2];
    const float* rtab = (const float*)d_in[3];
    const float* Wq   = (const float*)d_in[4];
    const float* bq   = (const float*)d_in[5];
    const float* Wkv  = (const float*)d_in[6];
    const float* bkv  = (const float*)d_in[7];
    const float* Wo   = (const float*)d_in[8];
    const float* bo   = (const float*)d_in[9];
    const float* cw1  = (const float*)d_in[10];
    const float* cb1  = (const float*)d_in[11];
    const float* cw2  = (const float*)d_in[12];
    const float* cb2  = (const float*)d_in[13];
    const float* fw1  = (const float*)d_in[14];
    const float* fb1  = (const float*)d_in[15];
    const float* fw2  = (const float*)d_in[16];
    const float* fb2  = (const float*)d_in[17];
    const float* lng  = (const float*)d_in[18];
    const float* lnb  = (const float*)d_in[19];
    const int L = in_sizes[3] / 2;   // rel_coords_table is [L][2]
    const int ncpb = (L + 31) / 32;

    char* w = (char*)d_ws;
    auto alloc = [&](size_t bytes) { char* p = w; w += (bytes + 255) & ~(size_t)255; return p; };
    bf16* qt      = (bf16*)alloc(8192ull * 256 * 2);
    bf16* kvt     = (bf16*)alloc(8192ull * 256 * 2);
    bf16* qhb     = (bf16*)alloc(8192ull * 256 * 2);
    bf16* kvpb    = (bf16*)alloc(8192ull * 512 * 2);
    bf16* vTb     = (bf16*)alloc(8ull * 8 * 32 * 1024 * 2);
    bf16* attnb   = (bf16*)alloc(8192ull * 256 * 2);
    bf16* outb    = (bf16*)alloc(8192ull * 256 * 2);
    bf16* ffh     = (bf16*)alloc(8192ull * 1024 * 2);   // aliased: biasF before FFN1
    bf16* ysp     = (bf16*)alloc(8ull * 256 * 1024 * 2);
    bf16* WqT     = (bf16*)alloc(256ull * 256 * 2);
    bf16* WkvT    = (bf16*)alloc(512ull * 256 * 2);
    bf16* WoT     = (bf16*)alloc(256ull * 256 * 2);
    bf16* W1T     = (bf16*)alloc(1024ull * 256 * 2);
    bf16* W2T     = (bf16*)alloc(256ull * 1024 * 2);
    float* cpbb   = (float*)alloc((size_t)8 * L * 4);
    int*  bar     = (int*)alloc(1024);
    bf16* biasF   = ffh;   // 16.78 MB, dead before ffh is first written

    hipMemsetAsync(bar, 0, 1024, stream);   // per-barrier monotonic counters
    prep_kernel<<<dim3(ncpb + 768 + 4096), 256, 0, stream>>>(
        rtab, cw1, cb1, cw2, cb2, cpbb, L, ncpb,
        Wq, Wkv, Wo, fw1, fw2, WqT, WkvT, WoT, W1T, W2T,
        q, kv, qt, kvt);
    mid_kernel<<<dim3(NBLK), 256, 0, stream>>>(
        qt, WqT, bq, qhb, kvt, WkvT, bkv, kvpb, vTb,
        ridx, cpbb, biasF, L, attnb,
        WoT, bo, outb, W1T, fb1, ffh, W2T, fb2, lng, lnb, ysp, bar);
    upsample_kernel<<<dim3(32768), 256, 0, stream>>>(q, ysp, (float*)d_out);
}

// Round 10
// 188.729 us; speedup vs baseline: 4.6396x; 4.6396x over previous
//
#include <hip/hip_runtime.h>
#include <hip/hip_bf16.h>
#include <hip/hip_fp16.h>

typedef __hip_bfloat16 bf16;
typedef __attribute__((ext_vector_type(8))) __bf16 bf16x8;   // 8 bf16 = 4 VGPRs (MFMA A/B frag)
typedef __attribute__((ext_vector_type(4))) __bf16 bf16x4;   // 8B packed store
typedef __attribute__((ext_vector_type(4))) float f32x4;     // MFMA C/D frag
typedef __attribute__((ext_vector_type(4))) float f4;        // indexable float4

// async global->LDS, 16B per lane. LDS dest must be wave-uniform base (lane*16 auto).
__device__ __forceinline__ void gload_lds16(const bf16* g, bf16* l)
{
    __builtin_amdgcn_global_load_lds((const __attribute__((address_space(1))) void*)g,
                                     (__attribute__((address_space(3))) void*)l, 16, 0, 0);
}

// ---------------------------------------------------------------------------
// prep_kernel: fuses (a) CPB MLP, (b) 5 weight transposes (LDS 32x32 tile,
// coalesced both sides), (c) both downsamples. grid = ncpb + 768 + 4096.
// ---------------------------------------------------------------------------
__global__ __launch_bounds__(256) void prep_kernel(
    const float* __restrict__ tab, const float* __restrict__ w1, const float* __restrict__ b1,
    const float* __restrict__ w2, const float* __restrict__ b2, float* __restrict__ cpbout, int L, int ncpb,
    const float* __restrict__ Wq, const float* __restrict__ Wkv, const float* __restrict__ Wo,
    const float* __restrict__ fw1, const float* __restrict__ fw2,
    bf16* __restrict__ WqT, bf16* __restrict__ WkvT, bf16* __restrict__ WoT,
    bf16* __restrict__ W1T, bf16* __restrict__ W2T,
    const float* __restrict__ qsrc, const float* __restrict__ kvsrc,
    bf16* __restrict__ qdst, bf16* __restrict__ kvdst)
{
    __shared__ float o[32][33];
    const int t = threadIdx.x;
    int bid = blockIdx.x;
    if (bid < ncpb) {
        int l = bid * 32 + (t >> 3);
        int js = t & 7;
        bool valid = l < L;
        float t0 = valid ? tab[2 * l] : 0.f, t1 = valid ? tab[2 * l + 1] : 0.f;
        float acc[8];
#pragma unroll
        for (int hh = 0; hh < 8; ++hh) acc[hh] = 0.f;
        for (int j = js; j < 512; j += 8) {
            float hv = fmaxf(t0 * w1[j] + t1 * w1[512 + j] + b1[j], 0.f);
            f4 w2a = *(const f4*)&w2[j * 8];
            f4 w2b = *(const f4*)&w2[j * 8 + 4];
#pragma unroll
            for (int hh = 0; hh < 4; ++hh) { acc[hh] += hv * w2a[hh]; acc[4 + hh] += hv * w2b[hh]; }
        }
#pragma unroll
        for (int d = 1; d < 8; d <<= 1)
#pragma unroll
            for (int hh = 0; hh < 8; ++hh) acc[hh] += __shfl_xor(acc[hh], d);
        if (js == 0 && valid)
#pragma unroll
            for (int hh = 0; hh < 8; ++hh) cpbout[(size_t)hh * L + l] = acc[hh] + b2[hh];
        return;
    }
    bid -= ncpb;
    if (bid < 768) {
        // ---- weight transpose via 32x32 LDS tile: WT[n][k] = bf16(W[k][n]) ----
        const float* W; bf16* WT; int K, N, base;
        if (bid < 64)        { W = Wq;  WT = WqT;  K = 256;  N = 256;  base = 0; }
        else if (bid < 192)  { W = Wkv; WT = WkvT; K = 256;  N = 512;  base = 64; }
        else if (bid < 256)  { W = Wo;  WT = WoT;  K = 256;  N = 256;  base = 192; }
        else if (bid < 512)  { W = fw1; WT = W1T;  K = 256;  N = 1024; base = 256; }
        else                 { W = fw2; WT = W2T;  K = 1024; N = 256;  base = 512; }
        int lid = bid - base;
        int tn = N >> 5;
        int k0 = (lid / tn) << 5, n0 = (lid % tn) << 5;
        {
            int r = t >> 3, cc = (t & 7) * 4;
            *(f4*)&o[r][cc] = *(const f4*)&W[(size_t)(k0 + r) * N + n0 + cc];
        }
        __syncthreads();
        {
            int n = t >> 3, kk = (t & 7) * 4;
            bf16 tmp[4];
#pragma unroll
            for (int i = 0; i < 4; ++i) tmp[i] = (bf16)o[kk + i][n];
            *(bf16x4*)&WT[(size_t)(n0 + n) * K + k0 + kk] = *(const bf16x4*)tmp;
        }
        return;
    }
    bid -= 768;
    {
        const float* src = bid < 2048 ? qsrc : kvsrc;
        bf16* dst = bid < 2048 ? qdst : kvdst;
        int bb2 = bid & 2047;
        int cc = bb2 & 7, i = (bb2 >> 3) & 31, b = bb2 >> 8;
#pragma unroll
        for (int p = 0; p < 4; ++p) {
            int id = p * 256 + t;
            int c = id >> 5, j = id & 31;
            const float* r = src + ((size_t)(b * 256 + cc * 32 + c) * 128 + 4 * i + 1) * 128 + 4 * j;
            float4 r1 = *(const float4*)r;
            float4 r2 = *(const float4*)(r + 128);
            o[c][j] = 0.25f * (r1.y + r1.z + r2.y + r2.z);
        }
        __syncthreads();
        {
            int j = t >> 3, c4 = (t & 7) * 4;
            bf16 tmp[4];
#pragma unroll
            for (int k = 0; k < 4; ++k) tmp[k] = (bf16)fmaxf(o[c4 + k][j], 0.f);
            *(bf16x4*)&dst[(size_t)(b * 1024 + i * 32 + j) * 256 + cc * 32 + c4] = *(const bf16x4*)tmp;
        }
    }
}

// ---------------------------------------------------------------------------
// GEMM core (single-buffer): tile BM x BN, BK=64, 4 waves (2x2).
// Linear LDS dest + XOR-swizzled global source; read applies the same XOR.
// ---------------------------------------------------------------------------
template<int BM, int BN>
__device__ __forceinline__ void gemm_core(
    const bf16* __restrict__ A, const bf16* __restrict__ BT, int K,
    int m0, int n0, bf16* As, bf16* Bs, f32x4 (&acc)[BM / 32][BN / 32])
{
    constexpr int MI = BM / 32, NJ = BN / 32;
    const int tid = threadIdx.x;
    const int lane = tid & 63, wid = tid >> 6;
    const int lo = lane & 15, hi = lane >> 4;
    const int wr = wid >> 1, wc = wid & 1;
#pragma unroll
    for (int i = 0; i < MI; ++i)
#pragma unroll
        for (int j = 0; j < NJ; ++j) acc[i][j] = f32x4{0.f, 0.f, 0.f, 0.f};

    for (int k0 = 0; k0 < K; k0 += 64) {
        __syncthreads();
#pragma unroll
        for (int p = 0; p < BM / 32; ++p) {
            int f = p * 256 + wid * 64 + lane;
            int row = f >> 3, cs = f & 7;
            gload_lds16(&A[(size_t)(m0 + row) * K + k0 + ((cs ^ (row & 7)) * 8)],
                        As + (size_t)(p * 256 + wid * 64) * 8);
        }
#pragma unroll
        for (int p = 0; p < BN / 32; ++p) {
            int f = p * 256 + wid * 64 + lane;
            int row = f >> 3, cs = f & 7;
            gload_lds16(&BT[(size_t)(n0 + row) * K + k0 + ((cs ^ (row & 7)) * 8)],
                        Bs + (size_t)(p * 256 + wid * 64) * 8);
        }
        __syncthreads();   // drains vmcnt(0) for global_load_lds
        bf16x8 af[2][MI], bfr[2][NJ];
#pragma unroll
        for (int kk = 0; kk < 2; ++kk) {
#pragma unroll
            for (int i = 0; i < MI; ++i) {
                int row = wr * (BM / 2) + i * 16 + lo;
                af[kk][i] = *(const bf16x8*)&As[row * 64 + (((kk * 4 + hi) ^ (lo & 7)) * 8)];
            }
#pragma unroll
            for (int j = 0; j < NJ; ++j) {
                int row = wc * (BN / 2) + j * 16 + lo;
                bfr[kk][j] = *(const bf16x8*)&Bs[row * 64 + (((kk * 4 + hi) ^ (lo & 7)) * 8)];
            }
        }
#pragma unroll
        for (int kk = 0; kk < 2; ++kk)
#pragma unroll
            for (int i = 0; i < MI; ++i)
#pragma unroll
                for (int j = 0; j < NJ; ++j)
                    acc[i][j] = __builtin_amdgcn_mfma_f32_16x16x32_bf16(af[kk][i], bfr[kk][j], acc[i][j], 0, 0, 0);
    }
}

// ---------------------------------------------------------------------------
template<int BM, int BN>
__global__ __launch_bounds__(256) void gemm_bt(
    const bf16* __restrict__ A, const bf16* __restrict__ BT,
    const float* __restrict__ bias, bf16* __restrict__ Cb, float* __restrict__ Cf,
    const bf16* __restrict__ resid, int M, int N, int K, int act)
{
    constexpr int MI = BM / 32, NJ = BN / 32;
    __shared__ __align__(16) bf16 As[BM * 64];
    __shared__ __align__(16) bf16 Bs[BN * 64];
    const int tid = threadIdx.x;
    const int lane = tid & 63, wid = tid >> 6;
    const int lo = lane & 15, hi = lane >> 4;
    const int m0 = blockIdx.x * BM, n0 = blockIdx.y * BN;
    const int wr = wid >> 1, wc = wid & 1;
    f32x4 acc[MI][NJ];
    gemm_core<BM, BN>(A, BT, K, m0, n0, As, Bs, acc);
#pragma unroll
    for (int i = 0; i < MI; ++i)
#pragma unroll
        for (int j = 0; j < NJ; ++j) {
            int col = n0 + wc * (BN / 2) + j * 16 + lo;
            float bv = bias[col];
#pragma unroll
            for (int r = 0; r < 4; ++r) {
                int row = m0 + wr * (BM / 2) + i * 16 + hi * 4 + r;
                float v = acc[i][j][r] + bv;
                if (act == 1) v = 0.5f * v * (1.f + erff(v * 0.70710678118654752f));
                if (resid) v += (float)resid[(size_t)row * N + col];
                if (Cb) Cb[(size_t)row * N + col] = (bf16)v;
                else    Cf[(size_t)row * N + col] = v;
            }
        }
}

// ---------------------------------------------------------------------------
// Fused q + kv projection + V-transpose epilogue + bias_gather rider.
// grid (128, 20). by<4 -> qh; by in [4,8) -> K-half; by in [8,12) -> V -> vT;
// by in [12,20) -> bias_gather blocks (id = (by-12)*128 + bx).
// ---------------------------------------------------------------------------
__global__ __launch_bounds__(256) void gemm_qkv(
    const bf16* __restrict__ qt, const bf16* __restrict__ WqT, const float* __restrict__ bq,
    bf16* __restrict__ qhb,
    const bf16* __restrict__ kvt, const bf16* __restrict__ WkvT, const float* __restrict__ bkv,
    bf16* __restrict__ kvpb, bf16* __restrict__ vT,
    const int* __restrict__ ridx, const float* __restrict__ cpbh,
    bf16* __restrict__ biasF, int L)
{
    __shared__ __align__(16) bf16 As[64 * 64];
    __shared__ __align__(16) bf16 Bs[64 * 64];
    const int tid = threadIdx.x;
    const int lane = tid & 63, wid = tid >> 6;
    const int lo = lane & 15, hi = lane >> 4;
    const int by = blockIdx.y;
    if (by >= 12) {
        // ---- bias_gather: fragment-ordered biasF[h][qt][mt][qj][lane][8] ----
        __shared__ int rix[32][32];
        int id = (by - 12) * 128 + blockIdx.x;
        int qtb = id >> 5, mt = id & 31;
        {
            int q = tid >> 3, m4 = (tid & 7) * 4;
            *(int4*)&rix[q][m4] = *(const int4*)&ridx[(size_t)(qtb * 32 + q) * 1024 + mt * 32 + m4];
        }
        __syncthreads();
        const int qj = (tid >> 6) & 1, hg = tid >> 7;
        int lidx[8];
#pragma unroll
        for (int j = 0; j < 8; ++j) {
            int kf = j >> 2, r = j & 3;
            lidx[j] = rix[qj * 16 + lo][kf * 16 + hi * 4 + r];
        }
#pragma unroll
        for (int hh = 0; hh < 4; ++hh) {
            int h = hg * 4 + hh;
            const float* ct = cpbh + (size_t)h * L;
            bf16 vals[8];
#pragma unroll
            for (int j = 0; j < 8; ++j) vals[j] = (bf16)ct[lidx[j]];
            size_t off = ((((size_t)(h * 32 + qtb) * 32 + mt) * 2 + qj) * 64 + lane) * 8;
            *(bf16x8*)&biasF[off] = *(const bf16x8*)vals;
        }
        return;
    }
    const int wr = wid >> 1, wc = wid & 1;
    const bf16 *A, *BT; const float* bias; int n0;
    if (by < 4)      { A = qt;  BT = WqT;  bias = bq;  n0 = by * 64; }
    else             { A = kvt; BT = WkvT; bias = bkv; n0 = (by - 4) * 64; }
    const int m0 = blockIdx.x * 64;
    f32x4 acc[2][2];
    gemm_core<64, 64>(A, BT, 256, m0, n0, As, Bs, acc);
#pragma unroll
    for (int i = 0; i < 2; ++i)
#pragma unroll
        for (int j = 0; j < 2; ++j) {
            int col = n0 + wc * 32 + j * 16 + lo;
            float bv = bias[col];
            if (by < 4) {
#pragma unroll
                for (int r = 0; r < 4; ++r) {
                    int row = m0 + wr * 32 + i * 16 + hi * 4 + r;
                    qhb[(size_t)row * 256 + col] = (bf16)(acc[i][j][r] + bv);
                }
            } else if (by < 8) {
#pragma unroll
                for (int r = 0; r < 4; ++r) {
                    int row = m0 + wr * 32 + i * 16 + hi * 4 + r;
                    kvpb[(size_t)row * 512 + col] = (bf16)(acc[i][j][r] + bv);
                }
            } else {
                int vcol = col - 256;
                int h = vcol >> 5, d = vcol & 31;
                int b = m0 >> 10;
                int mbase = (m0 & 1023) + wr * 32 + i * 16 + hi * 4;
                bf16 tmp[4];
#pragma unroll
                for (int r = 0; r < 4; ++r) tmp[r] = (bf16)(acc[i][j][r] + bv);
                *(bf16x4*)&vT[(size_t)((b * 8 + h) * 32 + d) * 1024 + mbase] = *(const bf16x4*)tmp;
            }
        }
}

// ---------------------------------------------------------------------------
// FFN2 + residual + LayerNorm + transpose, fused. BM=16 rows, grid 512
// (2 blocks/CU). Tile 16 x 256, K=1024, BK=64, 4 waves (1x4 col split).
// ---------------------------------------------------------------------------
__global__ __launch_bounds__(256) void ffn2_ln_kernel(
    const bf16* __restrict__ A, const bf16* __restrict__ BT,
    const float* __restrict__ bias, const bf16* __restrict__ resid,
    const float* __restrict__ g, const float* __restrict__ bb,
    bf16* __restrict__ ysp)
{
    __shared__ __align__(16) bf16 As[16 * 64];
    __shared__ __align__(16) bf16 Bs[256 * 64];
    __shared__ float buf[16][260];
    const int tid = threadIdx.x;
    const int lane = tid & 63, wid = tid >> 6;
    const int lo = lane & 15, hi = lane >> 4;
    const int m0 = blockIdx.x * 16;
    f32x4 acc[4];
#pragma unroll
    for (int j = 0; j < 4; ++j) acc[j] = f32x4{0.f, 0.f, 0.f, 0.f};

    for (int k0 = 0; k0 < 1024; k0 += 64) {
        __syncthreads();
        if (tid < 128) {   // A: 16 rows x 8 chunks (waves 0,1)
            int row = tid >> 3, cs = tid & 7;
            gload_lds16(&A[(size_t)(m0 + row) * 1024 + k0 + ((cs ^ (row & 7)) * 8)],
                        As + (size_t)(wid * 64) * 8);
        }
#pragma unroll
        for (int p = 0; p < 8; ++p) {   // B: 256 rows x 8 chunks
            int f = p * 256 + tid, row = f >> 3, cs = f & 7;
            gload_lds16(&BT[(size_t)row * 1024 + k0 + ((cs ^ (row & 7)) * 8)],
                        Bs + (size_t)(p * 256 + wid * 64) * 8);
        }
        __syncthreads();
        bf16x8 af[2], bfr[2][4];
#pragma unroll
        for (int kk = 0; kk < 2; ++kk) {
            af[kk] = *(const bf16x8*)&As[lo * 64 + (((kk * 4 + hi) ^ (lo & 7)) * 8)];
#pragma unroll
            for (int j = 0; j < 4; ++j) {
                int row = wid * 64 + j * 16 + lo;
                bfr[kk][j] = *(const bf16x8*)&Bs[row * 64 + (((kk * 4 + hi) ^ (lo & 7)) * 8)];
            }
        }
#pragma unroll
        for (int kk = 0; kk < 2; ++kk)
#pragma unroll
            for (int j = 0; j < 4; ++j)
                acc[j] = __builtin_amdgcn_mfma_f32_16x16x32_bf16(af[kk], bfr[kk][j], acc[j], 0, 0, 0);
    }
    // epilogue: z = acc + bias + resid -> buf[row][col]  (rows = hi*4+r)
#pragma unroll
    for (int j = 0; j < 4; ++j) {
        int col = wid * 64 + j * 16 + lo;
        float bv = bias[col];
#pragma unroll
        for (int r = 0; r < 4; ++r) {
            int lr = hi * 4 + r;
            buf[lr][col] = acc[j][r] + bv + (float)resid[(size_t)(m0 + lr) * 256 + col];
        }
    }
    __syncthreads();
#pragma unroll
    for (int rr = 0; rr < 4; ++rr) {
        int row = wid * 4 + rr;
        f4 x = *(const f4*)&buf[row][lane * 4];
        float s = x[0] + x[1] + x[2] + x[3];
#pragma unroll
        for (int d = 1; d < 64; d <<= 1) s += __shfl_xor(s, d);
        float mean = s * (1.f / 256.f);
        f4 dv = {x[0] - mean, x[1] - mean, x[2] - mean, x[3] - mean};
        float s2 = dv[0] * dv[0] + dv[1] * dv[1] + dv[2] * dv[2] + dv[3] * dv[3];
#pragma unroll
        for (int d = 1; d < 64; d <<= 1) s2 += __shfl_xor(s2, d);
        float rstd = rsqrtf(s2 * (1.f / 256.f) + 1e-5f);
        f4 o = {dv[0] * rstd, dv[1] * rstd, dv[2] * rstd, dv[3] * rstd};
        *(f4*)&buf[row][lane * 4] = o;
    }
    __syncthreads();
    float gc = g[tid], bc = bb[tid];
    int b = m0 >> 10, n0l = m0 & 1023;
    bf16* dst = &ysp[((size_t)(b * 256 + tid) << 10) + n0l];
#pragma unroll
    for (int p = 0; p < 2; ++p) {
        bf16 tmp[8];
#pragma unroll
        for (int k = 0; k < 8; ++k) tmp[k] = (bf16)(buf[p * 8 + k][tid] * gc + bc);
        *(bf16x8*)&dst[p * 8] = *(const bf16x8*)tmp;
    }
}

// ---------------------------------------------------------------------------
// Flash attention v3: swapped-QK orientation, key-split across 4 waves.
// grid (32 q-tiles, 8 heads, 8 batches); block = 4 waves.
// ---------------------------------------------------------------------------
__global__ __launch_bounds__(256) void attn_kernel(
    const bf16* __restrict__ qh, const bf16* __restrict__ kvp, const bf16* __restrict__ vT,
    const bf16* __restrict__ biasF, bf16* __restrict__ attnout)
{
    __shared__ __align__(16) bf16 Ps[4][32 * 40];
    __shared__ __align__(16) __half accs[4][32][34];   // [w][d][q]
    __shared__ float pm[4][32], pl[4][32];
    const int tid = threadIdx.x, lane = tid & 63, wid = tid >> 6;
    const int lo = lane & 15, hi = lane >> 4;
    const int qt = blockIdx.x, n0 = qt * 32;
    const int h = blockIdx.y;
    const int b = blockIdx.z;
    const float scale = 0.17677669529663687f;  // 1/sqrt(32)
    const f32x4 zero4 = {0.f, 0.f, 0.f, 0.f};

    bf16x8 qf[2];
#pragma unroll
    for (int qj = 0; qj < 2; ++qj)
        qf[qj] = *(const bf16x8*)&qh[(size_t)(b * 1024 + n0 + qj * 16 + lo) * 256 + h * 32 + hi * 8];

    f32x4 acc[2][2];  // [di][qj]: out^T[d][q]
#pragma unroll
    for (int i = 0; i < 2; ++i)
#pragma unroll
        for (int j = 0; j < 2; ++j) acc[i][j] = zero4;
    float mrow[2] = {-1e30f, -1e30f}, lrow[2] = {0.f, 0.f};

    bf16* Pw = Ps[wid];

    for (int t = wid; t < 32; t += 4) {
        const int m0 = t * 32;
        bf16x8 kfr0 = *(const bf16x8*)&kvp[(size_t)(b * 1024 + m0 + lo) * 512 + h * 32 + hi * 8];
        bf16x8 kfr1 = *(const bf16x8*)&kvp[(size_t)(b * 1024 + m0 + 16 + lo) * 512 + h * 32 + hi * 8];
        bf16x8 va0 = *(const bf16x8*)&vT[(size_t)((b * 8 + h) * 32 + lo) * 1024 + m0 + hi * 8];
        bf16x8 va1 = *(const bf16x8*)&vT[(size_t)((b * 8 + h) * 32 + 16 + lo) * 1024 + m0 + hi * 8];
        size_t boff = (((size_t)(h * 32 + qt) * 32 + t) * 2 * 64 + lane) * 8;
        bf16x8 bv0 = *(const bf16x8*)&biasF[boff];
        bf16x8 bv1 = *(const bf16x8*)&biasF[boff + 512];

        f32x4 s[2][2];  // [kf][qj]
        s[0][0] = __builtin_amdgcn_mfma_f32_16x16x32_bf16(kfr0, qf[0], zero4, 0, 0, 0);
        s[0][1] = __builtin_amdgcn_mfma_f32_16x16x32_bf16(kfr0, qf[1], zero4, 0, 0, 0);
        s[1][0] = __builtin_amdgcn_mfma_f32_16x16x32_bf16(kfr1, qf[0], zero4, 0, 0, 0);
        s[1][1] = __builtin_amdgcn_mfma_f32_16x16x32_bf16(kfr1, qf[1], zero4, 0, 0, 0);
#pragma unroll
        for (int kf = 0; kf < 2; ++kf)
#pragma unroll
            for (int r = 0; r < 4; ++r) {
                s[kf][0][r] = s[kf][0][r] * scale + (float)bv0[kf * 4 + r];
                s[kf][1][r] = s[kf][1][r] * scale + (float)bv1[kf * 4 + r];
            }
#pragma unroll
        for (int qj = 0; qj < 2; ++qj) {
            float mx = fmaxf(fmaxf(fmaxf(s[0][qj][0], s[0][qj][1]), fmaxf(s[0][qj][2], s[0][qj][3])),
                             fmaxf(fmaxf(s[1][qj][0], s[1][qj][1]), fmaxf(s[1][qj][2], s[1][qj][3])));
            mx = fmaxf(mx, __shfl_xor(mx, 16));
            mx = fmaxf(mx, __shfl_xor(mx, 32));
            float mnew = fmaxf(mrow[qj], mx);
            float alpha = __expf(mrow[qj] - mnew);
            float rs = 0.f;
#pragma unroll
            for (int kf = 0; kf < 2; ++kf)
#pragma unroll
                for (int r = 0; r < 4; ++r) {
                    float p = __expf(s[kf][qj][r] - mnew);
                    s[kf][qj][r] = p;
                    rs += p;
                }
            rs += __shfl_xor(rs, 16);
            rs += __shfl_xor(rs, 32);
            lrow[qj] = lrow[qj] * alpha + rs;
            mrow[qj] = mnew;
#pragma unroll
            for (int di = 0; di < 2; ++di)
#pragma unroll
                for (int r = 0; r < 4; ++r) acc[di][qj][r] *= alpha;
        }
#pragma unroll
        for (int qj = 0; qj < 2; ++qj)
#pragma unroll
            for (int kf = 0; kf < 2; ++kf)
#pragma unroll
                for (int r = 0; r < 4; ++r)
                    Pw[(qj * 16 + lo) * 40 + kf * 16 + hi * 4 + r] = (bf16)s[kf][qj][r];
        bf16x8 pb0 = *(const bf16x8*)&Pw[lo * 40 + hi * 8];
        bf16x8 pb1 = *(const bf16x8*)&Pw[(16 + lo) * 40 + hi * 8];
        acc[0][0] = __builtin_amdgcn_mfma_f32_16x16x32_bf16(va0, pb0, acc[0][0], 0, 0, 0);
        acc[0][1] = __builtin_amdgcn_mfma_f32_16x16x32_bf16(va0, pb1, acc[0][1], 0, 0, 0);
        acc[1][0] = __builtin_amdgcn_mfma_f32_16x16x32_bf16(va1, pb0, acc[1][0], 0, 0, 0);
        acc[1][1] = __builtin_amdgcn_mfma_f32_16x16x32_bf16(va1, pb1, acc[1][1], 0, 0, 0);
    }
#pragma unroll
    for (int di = 0; di < 2; ++di)
#pragma unroll
        for (int qj = 0; qj < 2; ++qj)
#pragma unroll
            for (int r = 0; r < 4; ++r)
                accs[wid][di * 16 + hi * 4 + r][qj * 16 + lo] = __float2half(acc[di][qj][r]);
    if (hi == 0) {
#pragma unroll
        for (int qj = 0; qj < 2; ++qj) {
            pm[wid][qj * 16 + lo] = mrow[qj];
            pl[wid][qj * 16 + lo] = lrow[qj];
        }
    }
    __syncthreads();
    int q = tid >> 3, d0 = (tid & 7) * 4;
    float M = fmaxf(fmaxf(pm[0][q], pm[1][q]), fmaxf(pm[2][q], pm[3][q]));
    float f0 = __expf(pm[0][q] - M), f1 = __expf(pm[1][q] - M);
    float f2 = __expf(pm[2][q] - M), f3 = __expf(pm[3][q] - M);
    float inv = 1.f / (pl[0][q] * f0 + pl[1][q] * f1 + pl[2][q] * f2 + pl[3][q] * f3);
    bf16 tmp[4];
#pragma unroll
    for (int j = 0; j < 4; ++j) {
        int d = d0 + j;
        float o = f0 * (float)accs[0][d][q] + f1 * (float)accs[1][d][q] +
                  f2 * (float)accs[2][d][q] + f3 * (float)accs[3][d][q];
        tmp[j] = (bf16)(o * inv);
    }
    *(bf16x4*)&attnout[(size_t)(b * 1024 + n0 + q) * 256 + h * 32 + d0] = *(const bf16x4*)tmp;
}

// ---------------------------------------------------------------------------
// Bilinear 32x32 -> 128x128 (align_corners=False, edge clamp) + ReLU + x.
// ysp is bf16 [B][C][1024].
// ---------------------------------------------------------------------------
__global__ __launch_bounds__(256) void upsample_kernel(const float* __restrict__ x,
    const bf16* __restrict__ ysp, float* __restrict__ out)
{
    int idx = blockIdx.x * 256 + threadIdx.x;
    int w4 = idx & 31; int r1 = idx >> 5;
    int hh = r1 & 127; int r2 = r1 >> 7;
    int c = r2 & 255; int b = r2 >> 8;
    float chh = 0.25f * hh - 0.375f;
    float fi = floorf(chh);
    float fh = chh - fi;
    int i0 = (int)fi;
    int ia = i0 < 0 ? 0 : i0;
    int ib = (i0 + 1) > 31 ? 31 : (i0 + 1);
    const bf16* yr = ysp + ((size_t)(b * 256 + c) << 10);
    const bf16* ra = yr + ia * 32;
    const bf16* rb = yr + ib * 32;
    f4 xv = *(const f4*)&x[(size_t)idx * 4];
    f4 o;
#pragma unroll
    for (int k = 0; k < 4; ++k) {
        int ww = w4 * 4 + k;
        float cww = 0.25f * ww - 0.375f;
        float fj = floorf(cww);
        float fw = cww - fj;
        int j0 = (int)fj;
        int ja = j0 < 0 ? 0 : j0;
        int jb = (j0 + 1) > 31 ? 31 : (j0 + 1);
        float v = (1.f - fh) * ((1.f - fw) * (float)ra[ja] + fw * (float)ra[jb]) +
                  fh * ((1.f - fw) * (float)rb[ja] + fw * (float)rb[jb]);
        o[k] = xv[k] + fmaxf(v, 0.f);
    }
    *(f4*)&out[(size_t)idx * 4] = o;
}

// ---------------------------------------------------------------------------
extern "C" void kernel_launch(void* const* d_in, const int* in_sizes, int n_in,
                              void* d_out, int out_size, void* d_ws, size_t ws_size,
                              hipStream_t stream)
{
    (void)n_in; (void)out_size; (void)ws_size;
    const float* q    = (const float*)d_in[0];
    const float* kv   = (const float*)d_in[1];
    const int*   ridx = (const int*)d_in[2];
    const float* rtab = (const float*)d_in[3];
    const float* Wq   = (const float*)d_in[4];
    const float* bq   = (const float*)d_in[5];
    const float* Wkv  = (const float*)d_in[6];
    const float* bkv  = (const float*)d_in[7];
    const float* Wo   = (const float*)d_in[8];
    const float* bo   = (const float*)d_in[9];
    const float* cw1  = (const float*)d_in[10];
    const float* cb1  = (const float*)d_in[11];
    const float* cw2  = (const float*)d_in[12];
    const float* cb2  = (const float*)d_in[13];
    const float* fw1  = (const float*)d_in[14];
    const float* fb1  = (const float*)d_in[15];
    const float* fw2  = (const float*)d_in[16];
    const float* fb2  = (const float*)d_in[17];
    const float* lng  = (const float*)d_in[18];
    const float* lnb  = (const float*)d_in[19];
    const int L = in_sizes[3] / 2;   // rel_coords_table is [L][2]
    const int ncpb = (L + 31) / 32;

    char* w = (char*)d_ws;
    auto alloc = [&](size_t bytes) { char* p = w; w += (bytes + 255) & ~(size_t)255; return p; };
    bf16* qt      = (bf16*)alloc(8192ull * 256 * 2);
    bf16* kvt     = (bf16*)alloc(8192ull * 256 * 2);
    bf16* qhb     = (bf16*)alloc(8192ull * 256 * 2);
    bf16* kvpb    = (bf16*)alloc(8192ull * 512 * 2);
    bf16* vTb     = (bf16*)alloc(8ull * 8 * 32 * 1024 * 2);
    bf16* attnb   = (bf16*)alloc(8192ull * 256 * 2);
    bf16* outb    = (bf16*)alloc(8192ull * 256 * 2);
    bf16* ffh     = (bf16*)alloc(8192ull * 1024 * 2);   // aliased: biasF before FFN1
    bf16* ysp     = (bf16*)alloc(8ull * 256 * 1024 * 2);
    bf16* WqT     = (bf16*)alloc(256ull * 256 * 2);
    bf16* WkvT    = (bf16*)alloc(512ull * 256 * 2);
    bf16* WoT     = (bf16*)alloc(256ull * 256 * 2);
    bf16* W1T     = (bf16*)alloc(1024ull * 256 * 2);
    bf16* W2T     = (bf16*)alloc(256ull * 1024 * 2);
    float* cpbb   = (float*)alloc((size_t)8 * L * 4);
    bf16* biasF   = ffh;   // 16.78 MB, dead before ffh is first written

    prep_kernel<<<dim3(ncpb + 768 + 4096), 256, 0, stream>>>(
        rtab, cw1, cb1, cw2, cb2, cpbb, L, ncpb,
        Wq, Wkv, Wo, fw1, fw2, WqT, WkvT, WoT, W1T, W2T,
        q, kv, qt, kvt);
    // qh/kv projections + V-transpose + bias_gather rider
    gemm_qkv<<<dim3(128, 20), 256, 0, stream>>>(qt, WqT, bq, qhb, kvt, WkvT, bkv, kvpb, vTb,
                                                ridx, cpbb, biasF, L);
    attn_kernel<<<dim3(32, 8, 8), 256, 0, stream>>>(qhb, kvpb, vTb, biasF, attnb);
    // out = attn @ Wo + bo
    gemm_bt<64, 64><<<dim3(128, 4), 256, 0, stream>>>(attnb, WoT, bo, outb, nullptr, nullptr, 8192, 256, 256, 0);
    // ffh = gelu(out @ ffn_w1 + b1)   (overwrites biasF — attn is done)
    gemm_bt<128, 64><<<dim3(64, 16), 256, 0, stream>>>(outb, W1T, fb1, ffh, nullptr, nullptr, 8192, 1024, 256, 1);
    // ysp = LN(ffh @ ffn_w2 + b2 + out) transposed, bf16
    ffn2_ln_kernel<<<dim3(512), 256, 0, stream>>>(ffh, W2T, fb2, outb, lng, lnb, ysp);
    upsample_kernel<<<dim3(32768), 256, 0, stream>>>(q, ysp, (float*)d_out);
}

// Round 11
// 173.087 us; speedup vs baseline: 5.0588x; 1.0904x over previous
//
#include <hip/hip_runtime.h>
#include <hip/hip_bf16.h>
#include <hip/hip_fp16.h>

typedef __hip_bfloat16 bf16;
typedef __attribute__((ext_vector_type(8))) __bf16 bf16x8;   // 8 bf16 = 4 VGPRs (MFMA A/B frag)
typedef __attribute__((ext_vector_type(4))) __bf16 bf16x4;   // 8B packed store
typedef __attribute__((ext_vector_type(4))) float f32x4;     // MFMA C/D frag
typedef __attribute__((ext_vector_type(4))) float f4;        // indexable float4

// async global->LDS, 16B per lane. LDS dest must be wave-uniform base (lane*16 auto).
__device__ __forceinline__ void gload_lds16(const bf16* g, bf16* l)
{
    __builtin_amdgcn_global_load_lds((const __attribute__((address_space(1))) void*)g,
                                     (__attribute__((address_space(3))) void*)l, 16, 0, 0);
}

// ---------------------------------------------------------------------------
// prep_kernel: fuses (a) CPB MLP, (b) 5 weight transposes (LDS 32x32 tile,
// coalesced both sides), (c) both downsamples. grid = ncpb + 768 + 4096.
// ---------------------------------------------------------------------------
__global__ __launch_bounds__(256) void prep_kernel(
    const float* __restrict__ tab, const float* __restrict__ w1, const float* __restrict__ b1,
    const float* __restrict__ w2, const float* __restrict__ b2, float* __restrict__ cpbout, int L, int ncpb,
    const float* __restrict__ Wq, const float* __restrict__ Wkv, const float* __restrict__ Wo,
    const float* __restrict__ fw1, const float* __restrict__ fw2,
    bf16* __restrict__ WqT, bf16* __restrict__ WkvT, bf16* __restrict__ WoT,
    bf16* __restrict__ W1T, bf16* __restrict__ W2T,
    const float* __restrict__ qsrc, const float* __restrict__ kvsrc,
    bf16* __restrict__ qdst, bf16* __restrict__ kvdst)
{
    __shared__ float o[32][33];
    const int t = threadIdx.x;
    int bid = blockIdx.x;
    if (bid < ncpb) {
        int l = bid * 32 + (t >> 3);
        int js = t & 7;
        bool valid = l < L;
        float t0 = valid ? tab[2 * l] : 0.f, t1 = valid ? tab[2 * l + 1] : 0.f;
        float acc[8];
#pragma unroll
        for (int hh = 0; hh < 8; ++hh) acc[hh] = 0.f;
        for (int j = js; j < 512; j += 8) {
            float hv = fmaxf(t0 * w1[j] + t1 * w1[512 + j] + b1[j], 0.f);
            f4 w2a = *(const f4*)&w2[j * 8];
            f4 w2b = *(const f4*)&w2[j * 8 + 4];
#pragma unroll
            for (int hh = 0; hh < 4; ++hh) { acc[hh] += hv * w2a[hh]; acc[4 + hh] += hv * w2b[hh]; }
        }
#pragma unroll
        for (int d = 1; d < 8; d <<= 1)
#pragma unroll
            for (int hh = 0; hh < 8; ++hh) acc[hh] += __shfl_xor(acc[hh], d);
        if (js == 0 && valid)
#pragma unroll
            for (int hh = 0; hh < 8; ++hh) cpbout[(size_t)hh * L + l] = acc[hh] + b2[hh];
        return;
    }
    bid -= ncpb;
    if (bid < 768) {
        // ---- weight transpose via 32x32 LDS tile: WT[n][k] = bf16(W[k][n]) ----
        const float* W; bf16* WT; int K, N, base;
        if (bid < 64)        { W = Wq;  WT = WqT;  K = 256;  N = 256;  base = 0; }
        else if (bid < 192)  { W = Wkv; WT = WkvT; K = 256;  N = 512;  base = 64; }
        else if (bid < 256)  { W = Wo;  WT = WoT;  K = 256;  N = 256;  base = 192; }
        else if (bid < 512)  { W = fw1; WT = W1T;  K = 256;  N = 1024; base = 256; }
        else                 { W = fw2; WT = W2T;  K = 1024; N = 256;  base = 512; }
        int lid = bid - base;
        int tn = N >> 5;
        int k0 = (lid / tn) << 5, n0 = (lid % tn) << 5;
        {
            int r = t >> 3, cc = (t & 7) * 4;
            *(f4*)&o[r][cc] = *(const f4*)&W[(size_t)(k0 + r) * N + n0 + cc];
        }
        __syncthreads();
        {
            int n = t >> 3, kk = (t & 7) * 4;
            bf16 tmp[4];
#pragma unroll
            for (int i = 0; i < 4; ++i) tmp[i] = (bf16)o[kk + i][n];
            *(bf16x4*)&WT[(size_t)(n0 + n) * K + k0 + kk] = *(const bf16x4*)tmp;
        }
        return;
    }
    bid -= 768;
    {
        const float* src = bid < 2048 ? qsrc : kvsrc;
        bf16* dst = bid < 2048 ? qdst : kvdst;
        int bb2 = bid & 2047;
        int cc = bb2 & 7, i = (bb2 >> 3) & 31, b = bb2 >> 8;
#pragma unroll
        for (int p = 0; p < 4; ++p) {
            int id = p * 256 + t;
            int c = id >> 5, j = id & 31;
            const float* r = src + ((size_t)(b * 256 + cc * 32 + c) * 128 + 4 * i + 1) * 128 + 4 * j;
            float4 r1 = *(const float4*)r;
            float4 r2 = *(const float4*)(r + 128);
            o[c][j] = 0.25f * (r1.y + r1.z + r2.y + r2.z);
        }
        __syncthreads();
        {
            int j = t >> 3, c4 = (t & 7) * 4;
            bf16 tmp[4];
#pragma unroll
            for (int k = 0; k < 4; ++k) tmp[k] = (bf16)fmaxf(o[c4 + k][j], 0.f);
            *(bf16x4*)&dst[(size_t)(b * 1024 + i * 32 + j) * 256 + cc * 32 + c4] = *(const bf16x4*)tmp;
        }
    }
}

// ---------------------------------------------------------------------------
// GEMM core (single-buffer): tile BM x BN, BK=64, 4 waves (2x2).
// Linear LDS dest + XOR-swizzled global source; read applies the same XOR.
// ---------------------------------------------------------------------------
template<int BM, int BN>
__device__ __forceinline__ void gemm_core(
    const bf16* __restrict__ A, const bf16* __restrict__ BT, int K,
    int m0, int n0, bf16* As, bf16* Bs, f32x4 (&acc)[BM / 32][BN / 32])
{
    constexpr int MI = BM / 32, NJ = BN / 32;
    const int tid = threadIdx.x;
    const int lane = tid & 63, wid = tid >> 6;
    const int lo = lane & 15, hi = lane >> 4;
    const int wr = wid >> 1, wc = wid & 1;
#pragma unroll
    for (int i = 0; i < MI; ++i)
#pragma unroll
        for (int j = 0; j < NJ; ++j) acc[i][j] = f32x4{0.f, 0.f, 0.f, 0.f};

    for (int k0 = 0; k0 < K; k0 += 64) {
        __syncthreads();
#pragma unroll
        for (int p = 0; p < BM / 32; ++p) {
            int f = p * 256 + wid * 64 + lane;
            int row = f >> 3, cs = f & 7;
            gload_lds16(&A[(size_t)(m0 + row) * K + k0 + ((cs ^ (row & 7)) * 8)],
                        As + (size_t)(p * 256 + wid * 64) * 8);
        }
#pragma unroll
        for (int p = 0; p < BN / 32; ++p) {
            int f = p * 256 + wid * 64 + lane;
            int row = f >> 3, cs = f & 7;
            gload_lds16(&BT[(size_t)(n0 + row) * K + k0 + ((cs ^ (row & 7)) * 8)],
                        Bs + (size_t)(p * 256 + wid * 64) * 8);
        }
        __syncthreads();   // drains vmcnt(0) for global_load_lds
        bf16x8 af[2][MI], bfr[2][NJ];
#pragma unroll
        for (int kk = 0; kk < 2; ++kk) {
#pragma unroll
            for (int i = 0; i < MI; ++i) {
                int row = wr * (BM / 2) + i * 16 + lo;
                af[kk][i] = *(const bf16x8*)&As[row * 64 + (((kk * 4 + hi) ^ (lo & 7)) * 8)];
            }
#pragma unroll
            for (int j = 0; j < NJ; ++j) {
                int row = wc * (BN / 2) + j * 16 + lo;
                bfr[kk][j] = *(const bf16x8*)&Bs[row * 64 + (((kk * 4 + hi) ^ (lo & 7)) * 8)];
            }
        }
#pragma unroll
        for (int kk = 0; kk < 2; ++kk)
#pragma unroll
            for (int i = 0; i < MI; ++i)
#pragma unroll
                for (int j = 0; j < NJ; ++j)
                    acc[i][j] = __builtin_amdgcn_mfma_f32_16x16x32_bf16(af[kk][i], bfr[kk][j], acc[i][j], 0, 0, 0);
    }
}

// ---------------------------------------------------------------------------
// SWAP=true transposes the grid mapping so consecutive blocks (x-major
// dispatch) share the same A-slab -> A stays hot in the XCD L2.
// ---------------------------------------------------------------------------
template<int BM, int BN, bool SWAP>
__global__ __launch_bounds__(256) void gemm_bt(
    const bf16* __restrict__ A, const bf16* __restrict__ BT,
    const float* __restrict__ bias, bf16* __restrict__ Cb, float* __restrict__ Cf,
    const bf16* __restrict__ resid, int M, int N, int K, int act)
{
    constexpr int MI = BM / 32, NJ = BN / 32;
    __shared__ __align__(16) bf16 As[BM * 64];
    __shared__ __align__(16) bf16 Bs[BN * 64];
    const int tid = threadIdx.x;
    const int lane = tid & 63, wid = tid >> 6;
    const int lo = lane & 15, hi = lane >> 4;
    const int m0 = (SWAP ? blockIdx.y : blockIdx.x) * BM;
    const int n0 = (SWAP ? blockIdx.x : blockIdx.y) * BN;
    const int wr = wid >> 1, wc = wid & 1;
    f32x4 acc[MI][NJ];
    gemm_core<BM, BN>(A, BT, K, m0, n0, As, Bs, acc);
#pragma unroll
    for (int i = 0; i < MI; ++i)
#pragma unroll
        for (int j = 0; j < NJ; ++j) {
            int col = n0 + wc * (BN / 2) + j * 16 + lo;
            float bv = bias[col];
#pragma unroll
            for (int r = 0; r < 4; ++r) {
                int row = m0 + wr * (BM / 2) + i * 16 + hi * 4 + r;
                float v = acc[i][j][r] + bv;
                if (act == 1) v = 0.5f * v * (1.f + erff(v * 0.70710678118654752f));
                if (resid) v += (float)resid[(size_t)row * N + col];
                if (Cb) Cb[(size_t)row * N + col] = (bf16)v;
                else    Cf[(size_t)row * N + col] = v;
            }
        }
}

// ---------------------------------------------------------------------------
// Fused q + kv projection + V-transpose epilogue + bias_gather rider.
// grid (128, 20). by<4 -> qh; by in [4,8) -> K-half; by in [8,12) -> V -> vT;
// by in [12,20) -> bias_gather blocks (id = (by-12)*128 + bx).
// ---------------------------------------------------------------------------
__global__ __launch_bounds__(256) void gemm_qkv(
    const bf16* __restrict__ qt, const bf16* __restrict__ WqT, const float* __restrict__ bq,
    bf16* __restrict__ qhb,
    const bf16* __restrict__ kvt, const bf16* __restrict__ WkvT, const float* __restrict__ bkv,
    bf16* __restrict__ kvpb, bf16* __restrict__ vT,
    const int* __restrict__ ridx, const float* __restrict__ cpbh,
    bf16* __restrict__ biasF, int L)
{
    __shared__ __align__(16) bf16 As[64 * 64];
    __shared__ __align__(16) bf16 Bs[64 * 64];
    const int tid = threadIdx.x;
    const int lane = tid & 63, wid = tid >> 6;
    const int lo = lane & 15, hi = lane >> 4;
    const int by = blockIdx.y;
    if (by >= 12) {
        // ---- bias_gather: fragment-ordered biasF[h][qt][mt][qj][lane][8] ----
        __shared__ int rix[32][32];
        int id = (by - 12) * 128 + blockIdx.x;
        int qtb = id >> 5, mt = id & 31;
        {
            int q = tid >> 3, m4 = (tid & 7) * 4;
            *(int4*)&rix[q][m4] = *(const int4*)&ridx[(size_t)(qtb * 32 + q) * 1024 + mt * 32 + m4];
        }
        __syncthreads();
        const int qj = (tid >> 6) & 1, hg = tid >> 7;
        int lidx[8];
#pragma unroll
        for (int j = 0; j < 8; ++j) {
            int kf = j >> 2, r = j & 3;
            lidx[j] = rix[qj * 16 + lo][kf * 16 + hi * 4 + r];
        }
#pragma unroll
        for (int hh = 0; hh < 4; ++hh) {
            int h = hg * 4 + hh;
            const float* ct = cpbh + (size_t)h * L;
            bf16 vals[8];
#pragma unroll
            for (int j = 0; j < 8; ++j) vals[j] = (bf16)ct[lidx[j]];
            size_t off = ((((size_t)(h * 32 + qtb) * 32 + mt) * 2 + qj) * 64 + lane) * 8;
            *(bf16x8*)&biasF[off] = *(const bf16x8*)vals;
        }
        return;
    }
    const int wr = wid >> 1, wc = wid & 1;
    const bf16 *A, *BT; const float* bias; int n0;
    if (by < 4)      { A = qt;  BT = WqT;  bias = bq;  n0 = by * 64; }
    else             { A = kvt; BT = WkvT; bias = bkv; n0 = (by - 4) * 64; }
    const int m0 = blockIdx.x * 64;
    f32x4 acc[2][2];
    gemm_core<64, 64>(A, BT, 256, m0, n0, As, Bs, acc);
#pragma unroll
    for (int i = 0; i < 2; ++i)
#pragma unroll
        for (int j = 0; j < 2; ++j) {
            int col = n0 + wc * 32 + j * 16 + lo;
            float bv = bias[col];
            if (by < 4) {
#pragma unroll
                for (int r = 0; r < 4; ++r) {
                    int row = m0 + wr * 32 + i * 16 + hi * 4 + r;
                    qhb[(size_t)row * 256 + col] = (bf16)(acc[i][j][r] + bv);
                }
            } else if (by < 8) {
#pragma unroll
                for (int r = 0; r < 4; ++r) {
                    int row = m0 + wr * 32 + i * 16 + hi * 4 + r;
                    kvpb[(size_t)row * 512 + col] = (bf16)(acc[i][j][r] + bv);
                }
            } else {
                int vcol = col - 256;
                int h = vcol >> 5, d = vcol & 31;
                int b = m0 >> 10;
                int mbase = (m0 & 1023) + wr * 32 + i * 16 + hi * 4;
                bf16 tmp[4];
#pragma unroll
                for (int r = 0; r < 4; ++r) tmp[r] = (bf16)(acc[i][j][r] + bv);
                *(bf16x4*)&vT[(size_t)((b * 8 + h) * 32 + d) * 1024 + mbase] = *(const bf16x4*)tmp;
            }
        }
}

// ---------------------------------------------------------------------------
// FFN2 + residual + LayerNorm + transpose, fused. BM=16 rows, grid 512
// (2 blocks/CU). Tile 16 x 256, K=1024, BK=64, 4 waves (1x4 col split).
// ---------------------------------------------------------------------------
__global__ __launch_bounds__(256) void ffn2_ln_kernel(
    const bf16* __restrict__ A, const bf16* __restrict__ BT,
    const float* __restrict__ bias, const bf16* __restrict__ resid,
    const float* __restrict__ g, const float* __restrict__ bb,
    bf16* __restrict__ ysp)
{
    __shared__ __align__(16) bf16 As[16 * 64];
    __shared__ __align__(16) bf16 Bs[256 * 64];
    __shared__ float buf[16][260];
    const int tid = threadIdx.x;
    const int lane = tid & 63, wid = tid >> 6;
    const int lo = lane & 15, hi = lane >> 4;
    const int m0 = blockIdx.x * 16;
    f32x4 acc[4];
#pragma unroll
    for (int j = 0; j < 4; ++j) acc[j] = f32x4{0.f, 0.f, 0.f, 0.f};

    for (int k0 = 0; k0 < 1024; k0 += 64) {
        __syncthreads();
        if (tid < 128) {   // A: 16 rows x 8 chunks (waves 0,1)
            int row = tid >> 3, cs = tid & 7;
            gload_lds16(&A[(size_t)(m0 + row) * 1024 + k0 + ((cs ^ (row & 7)) * 8)],
                        As + (size_t)(wid * 64) * 8);
        }
#pragma unroll
        for (int p = 0; p < 8; ++p) {   // B: 256 rows x 8 chunks
            int f = p * 256 + tid, row = f >> 3, cs = f & 7;
            gload_lds16(&BT[(size_t)row * 1024 + k0 + ((cs ^ (row & 7)) * 8)],
                        Bs + (size_t)(p * 256 + wid * 64) * 8);
        }
        __syncthreads();
        bf16x8 af[2], bfr[2][4];
#pragma unroll
        for (int kk = 0; kk < 2; ++kk) {
            af[kk] = *(const bf16x8*)&As[lo * 64 + (((kk * 4 + hi) ^ (lo & 7)) * 8)];
#pragma unroll
            for (int j = 0; j < 4; ++j) {
                int row = wid * 64 + j * 16 + lo;
                bfr[kk][j] = *(const bf16x8*)&Bs[row * 64 + (((kk * 4 + hi) ^ (lo & 7)) * 8)];
            }
        }
#pragma unroll
        for (int kk = 0; kk < 2; ++kk)
#pragma unroll
            for (int j = 0; j < 4; ++j)
                acc[j] = __builtin_amdgcn_mfma_f32_16x16x32_bf16(af[kk], bfr[kk][j], acc[j], 0, 0, 0);
    }
    // epilogue: z = acc + bias + resid -> buf[row][col]  (rows = hi*4+r)
#pragma unroll
    for (int j = 0; j < 4; ++j) {
        int col = wid * 64 + j * 16 + lo;
        float bv = bias[col];
#pragma unroll
        for (int r = 0; r < 4; ++r) {
            int lr = hi * 4 + r;
            buf[lr][col] = acc[j][r] + bv + (float)resid[(size_t)(m0 + lr) * 256 + col];
        }
    }
    __syncthreads();
#pragma unroll
    for (int rr = 0; rr < 4; ++rr) {
        int row = wid * 4 + rr;
        f4 x = *(const f4*)&buf[row][lane * 4];
        float s = x[0] + x[1] + x[2] + x[3];
#pragma unroll
        for (int d = 1; d < 64; d <<= 1) s += __shfl_xor(s, d);
        float mean = s * (1.f / 256.f);
        f4 dv = {x[0] - mean, x[1] - mean, x[2] - mean, x[3] - mean};
        float s2 = dv[0] * dv[0] + dv[1] * dv[1] + dv[2] * dv[2] + dv[3] * dv[3];
#pragma unroll
        for (int d = 1; d < 64; d <<= 1) s2 += __shfl_xor(s2, d);
        float rstd = rsqrtf(s2 * (1.f / 256.f) + 1e-5f);
        f4 o = {dv[0] * rstd, dv[1] * rstd, dv[2] * rstd, dv[3] * rstd};
        *(f4*)&buf[row][lane * 4] = o;
    }
    __syncthreads();
    float gc = g[tid], bc = bb[tid];
    int b = m0 >> 10, n0l = m0 & 1023;
    bf16* dst = &ysp[((size_t)(b * 256 + tid) << 10) + n0l];
#pragma unroll
    for (int p = 0; p < 2; ++p) {
        bf16 tmp[8];
#pragma unroll
        for (int k = 0; k < 8; ++k) tmp[k] = (bf16)(buf[p * 8 + k][tid] * gc + bc);
        *(bf16x8*)&dst[p * 8] = *(const bf16x8*)tmp;
    }
}

// ---------------------------------------------------------------------------
// Flash attention v3: swapped-QK orientation, key-split across 4 waves.
// grid (32 q-tiles, 8 heads, 8 batches); block = 4 waves.
// s_setprio(1) wraps the MFMA clusters (T5: helps when waves run free).
// ---------------------------------------------------------------------------
__global__ __launch_bounds__(256) void attn_kernel(
    const bf16* __restrict__ qh, const bf16* __restrict__ kvp, const bf16* __restrict__ vT,
    const bf16* __restrict__ biasF, bf16* __restrict__ attnout)
{
    __shared__ __align__(16) bf16 Ps[4][32 * 40];
    __shared__ __align__(16) __half accs[4][32][34];   // [w][d][q]
    __shared__ float pm[4][32], pl[4][32];
    const int tid = threadIdx.x, lane = tid & 63, wid = tid >> 6;
    const int lo = lane & 15, hi = lane >> 4;
    const int qt = blockIdx.x, n0 = qt * 32;
    const int h = blockIdx.y;
    const int b = blockIdx.z;
    const float scale = 0.17677669529663687f;  // 1/sqrt(32)
    const f32x4 zero4 = {0.f, 0.f, 0.f, 0.f};

    bf16x8 qf[2];
#pragma unroll
    for (int qj = 0; qj < 2; ++qj)
        qf[qj] = *(const bf16x8*)&qh[(size_t)(b * 1024 + n0 + qj * 16 + lo) * 256 + h * 32 + hi * 8];

    f32x4 acc[2][2];  // [di][qj]: out^T[d][q]
#pragma unroll
    for (int i = 0; i < 2; ++i)
#pragma unroll
        for (int j = 0; j < 2; ++j) acc[i][j] = zero4;
    float mrow[2] = {-1e30f, -1e30f}, lrow[2] = {0.f, 0.f};

    bf16* Pw = Ps[wid];

    for (int t = wid; t < 32; t += 4) {
        const int m0 = t * 32;
        bf16x8 kfr0 = *(const bf16x8*)&kvp[(size_t)(b * 1024 + m0 + lo) * 512 + h * 32 + hi * 8];
        bf16x8 kfr1 = *(const bf16x8*)&kvp[(size_t)(b * 1024 + m0 + 16 + lo) * 512 + h * 32 + hi * 8];
        bf16x8 va0 = *(const bf16x8*)&vT[(size_t)((b * 8 + h) * 32 + lo) * 1024 + m0 + hi * 8];
        bf16x8 va1 = *(const bf16x8*)&vT[(size_t)((b * 8 + h) * 32 + 16 + lo) * 1024 + m0 + hi * 8];
        size_t boff = (((size_t)(h * 32 + qt) * 32 + t) * 2 * 64 + lane) * 8;
        bf16x8 bv0 = *(const bf16x8*)&biasF[boff];
        bf16x8 bv1 = *(const bf16x8*)&biasF[boff + 512];

        f32x4 s[2][2];  // [kf][qj]
        __builtin_amdgcn_s_setprio(1);
        s[0][0] = __builtin_amdgcn_mfma_f32_16x16x32_bf16(kfr0, qf[0], zero4, 0, 0, 0);
        s[0][1] = __builtin_amdgcn_mfma_f32_16x16x32_bf16(kfr0, qf[1], zero4, 0, 0, 0);
        s[1][0] = __builtin_amdgcn_mfma_f32_16x16x32_bf16(kfr1, qf[0], zero4, 0, 0, 0);
        s[1][1] = __builtin_amdgcn_mfma_f32_16x16x32_bf16(kfr1, qf[1], zero4, 0, 0, 0);
        __builtin_amdgcn_s_setprio(0);
#pragma unroll
        for (int kf = 0; kf < 2; ++kf)
#pragma unroll
            for (int r = 0; r < 4; ++r) {
                s[kf][0][r] = s[kf][0][r] * scale + (float)bv0[kf * 4 + r];
                s[kf][1][r] = s[kf][1][r] * scale + (float)bv1[kf * 4 + r];
            }
#pragma unroll
        for (int qj = 0; qj < 2; ++qj) {
            float mx = fmaxf(fmaxf(fmaxf(s[0][qj][0], s[0][qj][1]), fmaxf(s[0][qj][2], s[0][qj][3])),
                             fmaxf(fmaxf(s[1][qj][0], s[1][qj][1]), fmaxf(s[1][qj][2], s[1][qj][3])));
            mx = fmaxf(mx, __shfl_xor(mx, 16));
            mx = fmaxf(mx, __shfl_xor(mx, 32));
            float mnew = fmaxf(mrow[qj], mx);
            float alpha = __expf(mrow[qj] - mnew);
            float rs = 0.f;
#pragma unroll
            for (int kf = 0; kf < 2; ++kf)
#pragma unroll
                for (int r = 0; r < 4; ++r) {
                    float p = __expf(s[kf][qj][r] - mnew);
                    s[kf][qj][r] = p;
                    rs += p;
                }
            rs += __shfl_xor(rs, 16);
            rs += __shfl_xor(rs, 32);
            lrow[qj] = lrow[qj] * alpha + rs;
            mrow[qj] = mnew;
#pragma unroll
            for (int di = 0; di < 2; ++di)
#pragma unroll
                for (int r = 0; r < 4; ++r) acc[di][qj][r] *= alpha;
        }
#pragma unroll
        for (int qj = 0; qj < 2; ++qj)
#pragma unroll
            for (int kf = 0; kf < 2; ++kf)
#pragma unroll
                for (int r = 0; r < 4; ++r)
                    Pw[(qj * 16 + lo) * 40 + kf * 16 + hi * 4 + r] = (bf16)s[kf][qj][r];
        bf16x8 pb0 = *(const bf16x8*)&Pw[lo * 40 + hi * 8];
        bf16x8 pb1 = *(const bf16x8*)&Pw[(16 + lo) * 40 + hi * 8];
        __builtin_amdgcn_s_setprio(1);
        acc[0][0] = __builtin_amdgcn_mfma_f32_16x16x32_bf16(va0, pb0, acc[0][0], 0, 0, 0);
        acc[0][1] = __builtin_amdgcn_mfma_f32_16x16x32_bf16(va0, pb1, acc[0][1], 0, 0, 0);
        acc[1][0] = __builtin_amdgcn_mfma_f32_16x16x32_bf16(va1, pb0, acc[1][0], 0, 0, 0);
        acc[1][1] = __builtin_amdgcn_mfma_f32_16x16x32_bf16(va1, pb1, acc[1][1], 0, 0, 0);
        __builtin_amdgcn_s_setprio(0);
    }
#pragma unroll
    for (int di = 0; di < 2; ++di)
#pragma unroll
        for (int qj = 0; qj < 2; ++qj)
#pragma unroll
            for (int r = 0; r < 4; ++r)
                accs[wid][di * 16 + hi * 4 + r][qj * 16 + lo] = __float2half(acc[di][qj][r]);
    if (hi == 0) {
#pragma unroll
        for (int qj = 0; qj < 2; ++qj) {
            pm[wid][qj * 16 + lo] = mrow[qj];
            pl[wid][qj * 16 + lo] = lrow[qj];
        }
    }
    __syncthreads();
    int q = tid >> 3, d0 = (tid & 7) * 4;
    float M = fmaxf(fmaxf(pm[0][q], pm[1][q]), fmaxf(pm[2][q], pm[3][q]));
    float f0 = __expf(pm[0][q] - M), f1 = __expf(pm[1][q] - M);
    float f2 = __expf(pm[2][q] - M), f3 = __expf(pm[3][q] - M);
    float inv = 1.f / (pl[0][q] * f0 + pl[1][q] * f1 + pl[2][q] * f2 + pl[3][q] * f3);
    bf16 tmp[4];
#pragma unroll
    for (int j = 0; j < 4; ++j) {
        int d = d0 + j;
        float o = f0 * (float)accs[0][d][q] + f1 * (float)accs[1][d][q] +
                  f2 * (float)accs[2][d][q] + f3 * (float)accs[3][d][q];
        tmp[j] = (bf16)(o * inv);
    }
    *(bf16x4*)&attnout[(size_t)(b * 1024 + n0 + q) * 256 + h * 32 + d0] = *(const bf16x4*)tmp;
}

// ---------------------------------------------------------------------------
// Upsample v2: bilinear 32->128 with the exact-4x structure exploited.
// For ww = 4m+k: fw[k] = {0.625,0.875,0.125,0.375}, src col j0 = m-1 (k<2)
// or m (k>=2); same for rows. 6 y-loads per thread instead of 16, no floorf.
// + ReLU + residual; non-temporal f4 store (out never re-read).
// ---------------------------------------------------------------------------
__global__ __launch_bounds__(256) void upsample_kernel(const float* __restrict__ x,
    const bf16* __restrict__ ysp, float* __restrict__ out)
{
    int idx = blockIdx.x * 256 + threadIdx.x;
    int m = idx & 31; int r1 = idx >> 5;
    int hh = r1 & 127; int r2 = r1 >> 7;
    int c = r2 & 255; int b = r2 >> 8;
    const int rr = hh & 3, n = hh >> 2;
    // row indices + weight (clamped at edges)
    const float fh = (rr == 0) ? 0.625f : (rr == 1) ? 0.875f : (rr == 2) ? 0.125f : 0.375f;
    int i0 = n + ((rr >= 2) ? 0 : -1);
    int ia = i0 < 0 ? 0 : i0;
    int ib = (i0 + 1) > 31 ? 31 : (i0 + 1);
    const bf16* yr = ysp + ((size_t)(b * 256 + c) << 10);
    const bf16* ra = yr + ia * 32;
    const bf16* rb = yr + ib * 32;
    int jm1 = m > 0 ? m - 1 : 0;
    int jp1 = m < 31 ? m + 1 : 31;
    float am1 = (float)ra[jm1], a0 = (float)ra[m], ap1 = (float)ra[jp1];
    float bm1 = (float)rb[jm1], b0 = (float)rb[m], bp1 = (float)rb[jp1];
    const float gh = 1.f - fh;
    f4 xv = *(const f4*)&x[(size_t)idx * 4];
    f4 o;
    // k=0: fw=0.625 cols (m-1,m); k=1: fw=0.875; k=2: fw=0.125 cols (m,m+1); k=3: fw=0.375
    {
        float ta = 0.375f * am1 + 0.625f * a0, tb = 0.375f * bm1 + 0.625f * b0;
        o[0] = xv[0] + fmaxf(gh * ta + fh * tb, 0.f);
    }
    {
        float ta = 0.125f * am1 + 0.875f * a0, tb = 0.125f * bm1 + 0.875f * b0;
        o[1] = xv[1] + fmaxf(gh * ta + fh * tb, 0.f);
    }
    {
        float ta = 0.875f * a0 + 0.125f * ap1, tb = 0.875f * b0 + 0.125f * bp1;
        o[2] = xv[2] + fmaxf(gh * ta + fh * tb, 0.f);
    }
    {
        float ta = 0.625f * a0 + 0.375f * ap1, tb = 0.625f * b0 + 0.375f * bp1;
        o[3] = xv[3] + fmaxf(gh * ta + fh * tb, 0.f);
    }
    __builtin_nontemporal_store(o, (f4*)&out[(size_t)idx * 4]);
}

// ---------------------------------------------------------------------------
extern "C" void kernel_launch(void* const* d_in, const int* in_sizes, int n_in,
                              void* d_out, int out_size, void* d_ws, size_t ws_size,
                              hipStream_t stream)
{
    (void)n_in; (void)out_size; (void)ws_size;
    const float* q    = (const float*)d_in[0];
    const float* kv   = (const float*)d_in[1];
    const int*   ridx = (const int*)d_in[2];
    const float* rtab = (const float*)d_in[3];
    const float* Wq   = (const float*)d_in[4];
    const float* bq   = (const float*)d_in[5];
    const float* Wkv  = (const float*)d_in[6];
    const float* bkv  = (const float*)d_in[7];
    const float* Wo   = (const float*)d_in[8];
    const float* bo   = (const float*)d_in[9];
    const float* cw1  = (const float*)d_in[10];
    const float* cb1  = (const float*)d_in[11];
    const float* cw2  = (const float*)d_in[12];
    const float* cb2  = (const float*)d_in[13];
    const float* fw1  = (const float*)d_in[14];
    const float* fb1  = (const float*)d_in[15];
    const float* fw2  = (const float*)d_in[16];
    const float* fb2  = (const float*)d_in[17];
    const float* lng  = (const float*)d_in[18];
    const float* lnb  = (const float*)d_in[19];
    const int L = in_sizes[3] / 2;   // rel_coords_table is [L][2]
    const int ncpb = (L + 31) / 32;

    char* w = (char*)d_ws;
    auto alloc = [&](size_t bytes) { char* p = w; w += (bytes + 255) & ~(size_t)255; return p; };
    bf16* qt      = (bf16*)alloc(8192ull * 256 * 2);
    bf16* kvt     = (bf16*)alloc(8192ull * 256 * 2);
    bf16* qhb     = (bf16*)alloc(8192ull * 256 * 2);
    bf16* kvpb    = (bf16*)alloc(8192ull * 512 * 2);
    bf16* vTb     = (bf16*)alloc(8ull * 8 * 32 * 1024 * 2);
    bf16* attnb   = (bf16*)alloc(8192ull * 256 * 2);
    bf16* outb    = (bf16*)alloc(8192ull * 256 * 2);
    bf16* ffh     = (bf16*)alloc(8192ull * 1024 * 2);   // aliased: biasF before FFN1
    bf16* ysp     = (bf16*)alloc(8ull * 256 * 1024 * 2);
    bf16* WqT     = (bf16*)alloc(256ull * 256 * 2);
    bf16* WkvT    = (bf16*)alloc(512ull * 256 * 2);
    bf16* WoT     = (bf16*)alloc(256ull * 256 * 2);
    bf16* W1T     = (bf16*)alloc(1024ull * 256 * 2);
    bf16* W2T     = (bf16*)alloc(256ull * 1024 * 2);
    float* cpbb   = (float*)alloc((size_t)8 * L * 4);
    bf16* biasF   = ffh;   // 16.78 MB, dead before ffh is first written

    prep_kernel<<<dim3(ncpb + 768 + 4096), 256, 0, stream>>>(
        rtab, cw1, cb1, cw2, cb2, cpbb, L, ncpb,
        Wq, Wkv, Wo, fw1, fw2, WqT, WkvT, WoT, W1T, W2T,
        q, kv, qt, kvt);
    // qh/kv projections + V-transpose + bias_gather rider
    gemm_qkv<<<dim3(128, 20), 256, 0, stream>>>(qt, WqT, bq, qhb, kvt, WkvT, bkv, kvpb, vTb,
                                                ridx, cpbb, biasF, L);
    attn_kernel<<<dim3(32, 8, 8), 256, 0, stream>>>(qhb, kvpb, vTb, biasF, attnb);
    // out = attn @ Wo + bo
    gemm_bt<64, 64, false><<<dim3(128, 4), 256, 0, stream>>>(attnb, WoT, bo, outb, nullptr, nullptr, 8192, 256, 256, 0);
    // ffh = gelu(out @ ffn_w1 + b1)  — SWAP grid so consecutive blocks share the A-slab (L2-hot)
    gemm_bt<128, 64, true><<<dim3(16, 64), 256, 0, stream>>>(outb, W1T, fb1, ffh, nullptr, nullptr, 8192, 1024, 256, 1);
    // ysp = LN(ffh @ ffn_w2 + b2 + out) transposed, bf16
    ffn2_ln_kernel<<<dim3(512), 256, 0, stream>>>(ffh, W2T, fb2, outb, lng, lnb, ysp);
    upsample_kernel<<<dim3(32768), 256, 0, stream>>>(q, ysp, (float*)d_out);
}